// Round 14
// baseline (332.651 us; speedup 1.0000x reference)
//
#include <hip/hip_runtime.h>
#include <math.h>

#define TT 8
#define NNODES 20000
#define NEDGES 320000
#define FDIM 128
#define HDIM 128
#define BGR 64
#define NCLS 16
#define GR 128    // gemm rows per block
#define NCH 32    // K-chunks per timestep for k_pgemm
#define KC 640    // nodes per chunk
#define NB 157    // radix buckets of 128 nodes (157*128 = 20096 >= 20000)
#define CB 80     // edge chunks per timestep
#define EC 4000   // edges per chunk (80*4000 = 320000)

__device__ __forceinline__ float lrelu(float x) { return fmaxf(x, 0.2f * x); }
__device__ __forceinline__ float sigmoidf(float x) { return 1.0f / (1.0f + __expf(-x)); }
__device__ __forceinline__ float tanh_fast(float x) {
  return 1.0f - 2.0f / (__expf(2.0f * x) + 1.0f);
}
__device__ __forceinline__ unsigned short f2bf(float f) {   // RNE
  unsigned int u = __float_as_uint(f);
  unsigned int r = (u + 0x7fff + ((u >> 16) & 1)) >> 16;
  return (unsigned short)r;
}
__device__ __forceinline__ float bf_lo(unsigned int u) { return __uint_as_float(u << 16); }
__device__ __forceinline__ float bf_hi(unsigned int u) { return __uint_as_float(u & 0xffff0000u); }

// ---------------- GEMM: h = x @ W (fp32 VALU, h stored bf16).
// Fragment remap vs R10: thread (ty,tx) owns rows {ty*4+i, 64+ty*4+i} and cols
// {tx*4+j, 64+tx*4+j} -> every float4 LDS read lands 2 lanes/bank-group (free)
// instead of 4-way (was 7.1M SQ_LDS_BANK_CONFLICT). Per-element arithmetic
// (k-order, fp32 FMA) identical to R10 -> bit-identical h/as/ad/denom.
__global__ __launch_bounds__(256) void k_gemm(
    const float* __restrict__ x, const float* __restrict__ W,
    const float* __restrict__ att_s, const float* __restrict__ att_d,
    unsigned short* __restrict__ hb, float* __restrict__ as_, float* __restrict__ ad_,
    float* __restrict__ denom) {
  __shared__ float xsT[32][GR + 4];   // [k][row] stride 132
  __shared__ float ws[32][HDIM];      // [k][col] stride 128
  __shared__ float asl[GR], adl[GR];
  __shared__ float atts[HDIM], attd[HDIM];
  const int tid = threadIdx.x;
  const int row0 = blockIdx.x * GR;
  if (tid < GR) { asl[tid] = 0.f; adl[tid] = 0.f; }
  if (tid < 128) { atts[tid] = att_s[tid]; attd[tid] = att_d[tid]; }
  const int ty = tid >> 4;   // rows {ty*4..+3} and {64+ty*4..+3}
  const int tx = tid & 15;   // cols {tx*4..+3} and {64+tx*4..+3}
  float acc[8][8] = {};
  for (int kb = 0; kb < 4; ++kb) {
    __syncthreads();
    #pragma unroll
    for (int p = 0; p < 4; ++p) {   // x tile: 128 rows x 32 k, transposed store
      int idx = tid + p * 256;
      int r = idx >> 3, k4 = idx & 7;
      float4 v = *(const float4*)(x + (size_t)(row0 + r) * FDIM + kb * 32 + k4 * 4);
      xsT[k4 * 4 + 0][r] = v.x; xsT[k4 * 4 + 1][r] = v.y;
      xsT[k4 * 4 + 2][r] = v.z; xsT[k4 * 4 + 3][r] = v.w;
    }
    #pragma unroll
    for (int p = 0; p < 4; ++p) {   // W tile
      int kr = (tid >> 5) + p * 8;
      int c4 = (tid & 31) * 4;
      *(float4*)(&ws[kr][c4]) = *(const float4*)(W + (size_t)(kb * 32 + kr) * HDIM + c4);
    }
    __syncthreads();
    #pragma unroll
    for (int k = 0; k < 32; ++k) {
      float a[8], bb[8];
      *(float4*)&a[0]  = *(const float4*)(&xsT[k][ty * 4]);
      *(float4*)&a[4]  = *(const float4*)(&xsT[k][64 + ty * 4]);
      *(float4*)&bb[0] = *(const float4*)(&ws[k][tx * 4]);
      *(float4*)&bb[4] = *(const float4*)(&ws[k][64 + tx * 4]);
      #pragma unroll
      for (int i = 0; i < 8; ++i)
        #pragma unroll
        for (int j = 0; j < 8; ++j)
          acc[i][j] += a[i] * bb[j];
    }
  }
  float av[8], dv[8];
  *(float4*)&av[0] = *(const float4*)(&atts[tx * 4]);
  *(float4*)&av[4] = *(const float4*)(&atts[64 + tx * 4]);
  *(float4*)&dv[0] = *(const float4*)(&attd[tx * 4]);
  *(float4*)&dv[4] = *(const float4*)(&attd[64 + tx * 4]);
  #pragma unroll
  for (int i = 0; i < 8; ++i) {
    int lr = (i < 4) ? (ty * 4 + i) : (64 + ty * 4 + (i - 4));
    int row = row0 + lr;
    float ps = 0.f, pd = 0.f;
    #pragma unroll
    for (int j = 0; j < 8; ++j) { ps += acc[i][j] * av[j]; pd += acc[i][j] * dv[j]; }
    uint2 p0, p1;
    p0.x = (unsigned int)f2bf(acc[i][0]) | ((unsigned int)f2bf(acc[i][1]) << 16);
    p0.y = (unsigned int)f2bf(acc[i][2]) | ((unsigned int)f2bf(acc[i][3]) << 16);
    p1.x = (unsigned int)f2bf(acc[i][4]) | ((unsigned int)f2bf(acc[i][5]) << 16);
    p1.y = (unsigned int)f2bf(acc[i][6]) | ((unsigned int)f2bf(acc[i][7]) << 16);
    *(uint2*)(hb + (size_t)row * HDIM + tx * 4)      = p0;
    *(uint2*)(hb + (size_t)row * HDIM + 64 + tx * 4) = p1;
    atomicAdd(&asl[lr], ps);
    atomicAdd(&adl[lr], pd);
  }
  __syncthreads();
  if (tid < GR) {
    float a = asl[tid], d = adl[tid];
    as_[row0 + tid] = a;
    ad_[row0 + tid] = d;
    denom[row0 + tid] = __expf(lrelu(a + d));   // self-loop seeds denominator
  }
}

// ---------------- radix pass A: per-(t,chunk) bucket histograms, keyed by dst AND src
__global__ __launch_bounds__(256) void k_pA(const int* __restrict__ ei,
                                            int* __restrict__ gcnt_d, int* __restrict__ gcnt_s) {
  __shared__ int hd[NB], hs[NB];
  const int tid = threadIdx.x;
  const int chunk = blockIdx.x, t = blockIdx.y;
  if (tid < NB) { hd[tid] = 0; hs[tid] = 0; }
  __syncthreads();
  const int* eis = ei + (size_t)t * 2 * NEDGES;
  for (int i = tid; i < EC; i += 256) {
    int e = chunk * EC + i;
    int s = eis[e], d = eis[NEDGES + e];
    atomicAdd(&hd[d >> 7], 1);
    atomicAdd(&hs[s >> 7], 1);
  }
  __syncthreads();
  if (tid < NB) {
    gcnt_d[((size_t)t * CB + chunk) * NB + tid] = hd[tid];
    gcnt_s[((size_t)t * CB + chunk) * NB + tid] = hs[tid];
  }
}

// ---------------- radix pass B: per-(t,axis) exclusive scan -> goff[t][bucket][chunk]
__global__ __launch_bounds__(256) void k_pB(const int* __restrict__ gcnt_d, const int* __restrict__ gcnt_s,
                                            int* __restrict__ goff_d, int* __restrict__ goff_s) {
  const int t = blockIdx.x >> 1, axis = blockIdx.x & 1;
  const int tid = threadIdx.x;
  const int* gc = axis ? gcnt_s : gcnt_d;
  int* go = axis ? goff_s : goff_d;
  __shared__ int tot[NB];
  __shared__ int base[NB];
  if (tid < NB) {
    int s = 0;
    for (int c = 0; c < CB; ++c) s += gc[((size_t)t * CB + c) * NB + tid];
    tot[tid] = s;
  }
  __syncthreads();
  if (tid == 0) {
    int run = 0;
    for (int B = 0; B < NB; ++B) { base[B] = run; run += tot[B]; }
  }
  __syncthreads();
  if (tid < NB) {
    int run = base[tid];
    for (int c = 0; c < CB; ++c) {
      go[((size_t)t * NB + tid) * CB + c] = run;
      run += gc[((size_t)t * CB + c) * NB + tid];
    }
  }
}

// ---------------- radix pass C: scatter packed records into both partitions (LDS cursors)
__global__ __launch_bounds__(256) void k_pC(const int* __restrict__ ei,
                                            const int* __restrict__ goff_d, const int* __restrict__ goff_s,
                                            unsigned int* __restrict__ part_d, unsigned int* __restrict__ part_s) {
  __shared__ int cd[NB], cs2[NB];
  const int tid = threadIdx.x;
  const int chunk = blockIdx.x, t = blockIdx.y;
  if (tid < NB) {
    cd[tid]  = goff_d[((size_t)t * NB + tid) * CB + chunk];
    cs2[tid] = goff_s[((size_t)t * NB + tid) * CB + chunk];
  }
  __syncthreads();
  const int* eis = ei + (size_t)t * 2 * NEDGES;
  unsigned int* pdt = part_d + (size_t)t * NEDGES;
  unsigned int* pst = part_s + (size_t)t * NEDGES;
  for (int i = tid; i < EC; i += 256) {
    int e = chunk * EC + i;
    int s = eis[e], d = eis[NEDGES + e];
    unsigned int rec = ((unsigned int)s << 15) | (unsigned int)d;
    int pd = atomicAdd(&cd[d >> 7], 1);
    pdt[pd] = rec;
    int ps = atomicAdd(&cs2[s >> 7], 1);
    pst[ps] = rec;
  }
}

// ---------------- denominator from dst-partition: LDS hist, plain-store flush
__global__ __launch_bounds__(256) void k_denomB(
    const unsigned int* __restrict__ part_d, const int* __restrict__ goff_d,
    const float* __restrict__ as_, const float* __restrict__ ad_, float* __restrict__ denom) {
  __shared__ float hist[128];
  __shared__ float adl[128];
  const int tid = threadIdx.x;
  const int B = blockIdx.x, t = blockIdx.y;
  if (tid < 128) {
    hist[tid] = 0.f;
    int n = B * 128 + tid;
    adl[tid] = (n < NNODES) ? ad_[t * NNODES + n] : 0.f;
  }
  __syncthreads();
  const int base = goff_d[((size_t)t * NB + B) * CB + 0];
  const int end  = (B + 1 < NB) ? goff_d[((size_t)t * NB + B + 1) * CB + 0] : NEDGES;
  const unsigned int* pdt = part_d + (size_t)t * NEDGES;
  const float* asb = as_ + (size_t)t * NNODES;
  for (int i = base + tid; i < end; i += 256) {
    unsigned int rec = pdt[i];
    int d = rec & 32767, s = rec >> 15;
    float w = __expf(lrelu(asb[s] + adl[d & 127]));
    atomicAdd(&hist[d & 127], w);
  }
  __syncthreads();
  if (tid < 128) {
    int n = B * 128 + tid;
    if (n < NNODES) denom[t * NNODES + n] += hist[tid];   // seed already there
  }
}

// ---------------- aux pack: (ad, 1/denom) per node
__global__ void k_dinvaux(const float* __restrict__ denom, const float* __restrict__ ad_,
                          float2* __restrict__ aux) {
  int i = blockIdx.x * 256 + threadIdx.x;   // 160000 / 256 = 625 exact
  aux[i] = make_float2(ad_[i], 1.0f / denom[i]);
}

// ---------------- batch segment starts (batch is sorted)
__global__ void k_starts(const int* __restrict__ batch, int* __restrict__ starts) {
  int n = blockIdx.x * 256 + threadIdx.x;
  if (n >= NNODES) return;
  int b = batch[n];
  if (n == 0) { for (int bb = 0; bb <= b; ++bb) starts[bb] = 0; }
  else { int pb = batch[n - 1]; for (int bb = pb + 1; bb <= b; ++bb) starts[bb] = n; }
  if (n == NNODES - 1) { for (int bb = b + 1; bb <= BGR; ++bb) starts[bb] = NNODES; }
}

// ---------------- c build from src-partition: LDS tile c_loc[64][128], plain-store flush
__global__ __launch_bounds__(256) void k_cbuildB(
    const unsigned int* __restrict__ part_s, const int* __restrict__ goff_s,
    const float* __restrict__ as_, const float2* __restrict__ aux,
    const int* __restrict__ batch, float* __restrict__ c) {
  __shared__ float cl[BGR * 128];   // 32 KB
  __shared__ float asl[128];
  const int tid = threadIdx.x;
  const int B = blockIdx.x, t = blockIdx.y;
  #pragma unroll
  for (int i = tid; i < BGR * 128; i += 256) cl[i] = 0.f;
  if (tid < 128) {
    int n = B * 128 + tid;
    asl[tid] = (n < NNODES) ? as_[t * NNODES + n] : 0.f;
  }
  __syncthreads();
  if (tid < 128) {   // self-loop coefficient
    int n = B * 128 + tid;
    if (n < NNODES) {
      float2 a2 = aux[t * NNODES + n];
      float wself = __expf(lrelu(asl[tid] + a2.x)) * a2.y;
      cl[batch[n] * 128 + tid] = wself;
    }
  }
  __syncthreads();
  const int base = goff_s[((size_t)t * NB + B) * CB + 0];
  const int end  = (B + 1 < NB) ? goff_s[((size_t)t * NB + B + 1) * CB + 0] : NEDGES;
  const unsigned int* pst = part_s + (size_t)t * NEDGES;
  const float2* auxt = aux + (size_t)t * NNODES;
  for (int i = base + tid; i < end; i += 256) {
    unsigned int rec = pst[i];
    int d = rec & 32767, s = rec >> 15;
    float2 a2 = auxt[d];
    float w = __expf(lrelu(asl[s & 127] + a2.x)) * a2.y;
    atomicAdd(&cl[batch[d] * 128 + (s & 127)], w);
  }
  __syncthreads();
  float* cb = c + (size_t)t * BGR * NNODES;
  #pragma unroll
  for (int idx = tid; idx < BGR * 128; idx += 256) {
    int b = idx >> 7, j = idx & 127;
    int col = B * 128 + j;
    if (col < NNODES) cb[(size_t)b * NNODES + col] = cl[idx];
  }
}

// ---------------- pooled = c @ h : per (t, K-chunk) block -> [64 x 128] partial
__global__ __launch_bounds__(256) void k_pgemm(
    const unsigned short* __restrict__ hb, const float* __restrict__ c,
    float* __restrict__ ppart) {
  __shared__ float cs[64][33];
  __shared__ unsigned int hs[32][64];
  const int tid = threadIdx.x;
  const int t = blockIdx.x >> 5;
  const int ch = blockIdx.x & (NCH - 1);
  const int k0 = ch * KC;
  const int k1 = min(k0 + KC, NNODES);
  const int bq = tid >> 4;
  const int dq = tid & 15;
  const float* cb = c + (size_t)t * BGR * NNODES;
  const unsigned short* hbase = hb + (size_t)t * NNODES * HDIM;
  float acc[4][8] = {};
  for (int kt = k0; kt < k1; kt += 32) {
    __syncthreads();
    #pragma unroll
    for (int p = 0; p < 2; ++p) {
      int idx = tid + p * 256;
      int b = idx >> 3, q = idx & 7;
      float4 v = *(const float4*)(cb + (size_t)b * NNODES + kt + q * 4);
      cs[b][q * 4 + 0] = v.x; cs[b][q * 4 + 1] = v.y;
      cs[b][q * 4 + 2] = v.z; cs[b][q * 4 + 3] = v.w;
    }
    #pragma unroll
    for (int p = 0; p < 2; ++p) {
      int idx = tid + p * 256;
      int r = idx >> 4, slot = idx & 15;
      uint4 v = *(const uint4*)(hbase + (size_t)(kt + r) * HDIM + slot * 8);
      *(uint4*)(&hs[r][slot * 4]) = v;
    }
    __syncthreads();
    #pragma unroll
    for (int kk = 0; kk < 32; ++kk) {
      float cv[4];
      #pragma unroll
      for (int i = 0; i < 4; ++i) cv[i] = cs[bq * 4 + i][kk];
      unsigned int hu[4];
      #pragma unroll
      for (int q = 0; q < 4; ++q) hu[q] = hs[kk][dq * 4 + q];
      float hd[8];
      #pragma unroll
      for (int q = 0; q < 4; ++q) { hd[2 * q] = bf_lo(hu[q]); hd[2 * q + 1] = bf_hi(hu[q]); }
      #pragma unroll
      for (int i = 0; i < 4; ++i)
        #pragma unroll
        for (int d = 0; d < 8; ++d)
          acc[i][d] += cv[i] * hd[d];
    }
  }
  float* pp = ppart + ((size_t)t * NCH + ch) * BGR * HDIM;
  #pragma unroll
  for (int i = 0; i < 4; ++i) {
    *(float4*)(pp + (bq * 4 + i) * HDIM + dq * 8)     = make_float4(acc[i][0], acc[i][1], acc[i][2], acc[i][3]);
    *(float4*)(pp + (bq * 4 + i) * HDIM + dq * 8 + 4) = make_float4(acc[i][4], acc[i][5], acc[i][6], acc[i][7]);
  }
}

// ---------------- LSTM over T + fused FC (one block per batch row b)
__global__ __launch_bounds__(512) void k_lstm_fc(
    const float* __restrict__ ppart, const int* __restrict__ starts,
    const float* __restrict__ gat_bias,
    const float* __restrict__ W_ih, const float* __restrict__ W_hh,
    const float* __restrict__ b_ih, const float* __restrict__ b_hh,
    const float* __restrict__ z, const float* __restrict__ fc_W,
    const float* __restrict__ fc_b, float* __restrict__ out) {
  const int b = blockIdx.x;
  const int g = threadIdx.x;
  __shared__ unsigned int wpk[512 * 65];
  __shared__ float hv[128], cv[128], part[512];
  __shared__ float pool8[TT][128];
  __shared__ float fcp[16][17];

  #pragma unroll 2
  for (int it = 0; it < 64; ++it) {
    int i = g + it * 512;
    int gr = i >> 6, j = i & 63;
    float2 wv = *(const float2*)(W_hh + (size_t)gr * HDIM + j * 2);
    wpk[gr * 65 + j] = (unsigned int)f2bf(wv.x) | ((unsigned int)f2bf(wv.y) << 16);
  }

  const int cntb = starts[b + 1] - starts[b];
  const float invc = 1.0f / (float)max(cntb, 1);
  #pragma unroll
  for (int i = 0; i < 2; ++i) {
    int idx = g + i * 512;
    int t = idx >> 7, k = idx & 127;
    const float* pp = ppart + ((size_t)t * NCH * BGR + b) * HDIM + k;
    float s = 0.f;
    #pragma unroll 8
    for (int ch = 0; ch < NCH; ++ch) s += pp[(size_t)ch * BGR * HDIM];
    pool8[t][k] = s * invc + gat_bias[k];
  }
  if (g < 128) { hv[g] = 0.f; cv[g] = 0.f; }
  __syncthreads();

  float gx[8] = {};
  {
    const float4* wi = (const float4*)(W_ih + (size_t)g * HDIM);
    #pragma unroll 2
    for (int k4 = 0; k4 < 32; ++k4) {
      float4 wv = wi[k4];
      #pragma unroll
      for (int t = 0; t < TT; ++t) {
        float4 p = *(const float4*)(&pool8[t][k4 * 4]);
        gx[t] += wv.x * p.x + wv.y * p.y + wv.z * p.z + wv.w * p.w;
      }
    }
  }
  const float bsum = b_ih[g] + b_hh[g];
  const unsigned int* wr = &wpk[g * 65];
  const float4* hv4 = (const float4*)hv;
  #pragma unroll
  for (int t = 0; t < TT; ++t) {
    float s = gx[t] + bsum;
    #pragma unroll 8
    for (int j2 = 0; j2 < 32; ++j2) {
      unsigned int w0 = wr[2 * j2], w1 = wr[2 * j2 + 1];
      float4 hh = hv4[j2];
      s += bf_lo(w0) * hh.x + bf_hi(w0) * hh.y + bf_lo(w1) * hh.z + bf_hi(w1) * hh.w;
    }
    part[g] = s;
    __syncthreads();
    if (g < 128) {
      float ig = sigmoidf(part[g]);
      float fg = sigmoidf(part[128 + g]);
      float gc = tanh_fast(part[256 + g]);
      float og = sigmoidf(part[384 + g]);
      float c = fg * cv[g] + ig * gc;
      cv[g] = c;
      hv[g] = og * tanh_fast(c);
    }
    __syncthreads();
  }
  if (g < 256) {
    const int c = g >> 4, kp = g & 15;
    float s = 0.f;
    for (int k = kp * 16; k < kp * 16 + 16; ++k) {
      float v = (k < 128) ? hv[k] : z[(size_t)b * HDIM + (k - 128)];
      s += v * fc_W[(size_t)c * 256 + k];
    }
    fcp[c][kp] = s;
  }
  __syncthreads();
  if (g < 16) {
    float r = fc_b[g];
    #pragma unroll
    for (int k = 0; k < 16; ++k) r += fcp[g][k];
    out[(size_t)b * NCLS + g] = r;
  }
}

extern "C" void kernel_launch(void* const* d_in, const int* in_sizes, int n_in,
                              void* d_out, int out_size, void* d_ws, size_t ws_size,
                              hipStream_t stream) {
  const float* x       = (const float*)d_in[0];
  const int*   ei      = (const int*)d_in[1];
  const int*   batch   = (const int*)d_in[2];
  const float* z       = (const float*)d_in[3];
  const float* gat_W   = (const float*)d_in[4];
  const float* att_src = (const float*)d_in[5];
  const float* att_dst = (const float*)d_in[6];
  const float* gat_bias= (const float*)d_in[7];
  const float* W_ih    = (const float*)d_in[8];
  const float* W_hh    = (const float*)d_in[9];
  const float* b_ih    = (const float*)d_in[10];
  const float* b_hh    = (const float*)d_in[11];
  const float* fc_W    = (const float*)d_in[12];
  const float* fc_b    = (const float*)d_in[13];
  float* out = (float*)d_out;

  char* ws = (char*)d_ws;
  size_t off = 0;
  auto alloc = [&](size_t bytes) {
    void* p = (void*)(ws + off);
    off += (bytes + 255) & ~(size_t)255;
    return p;
  };
  unsigned short* hbuf = (unsigned short*)alloc((size_t)TT * NNODES * HDIM * 2);  // 40.96 MB
  float*  as_    = (float*)alloc((size_t)TT * NNODES * 4);
  float*  ad_    = (float*)alloc((size_t)TT * NNODES * 4);
  float*  denom  = (float*)alloc((size_t)TT * NNODES * 4);
  float2* aux    = (float2*)alloc((size_t)TT * NNODES * 8);
  float*  cbuf   = (float*)alloc((size_t)TT * BGR * NNODES * 4);                  // 40.96 MB
  // partition region; ppart aliases its start (parts dead before k_pgemm writes)
  size_t parts_off = off;
  unsigned int* part_d = (unsigned int*)alloc((size_t)TT * NEDGES * 4);           // 10.24 MB
  unsigned int* part_s = (unsigned int*)alloc((size_t)TT * NEDGES * 4);           // 10.24 MB
  float* ppart = (float*)(ws + parts_off);
  int* gcnt_d = (int*)alloc((size_t)TT * CB * NB * 4);
  int* gcnt_s = (int*)alloc((size_t)TT * CB * NB * 4);
  int* goff_d = (int*)alloc((size_t)TT * NB * CB * 4);
  int* goff_s = (int*)alloc((size_t)TT * NB * CB * 4);
  int* starts = (int*)alloc((BGR + 1) * 4);
  (void)ws_size; (void)in_sizes; (void)n_in; (void)out_size;

  k_gemm<<<(TT * NNODES) / GR, 256, 0, stream>>>(x, gat_W, att_src, att_dst, hbuf, as_, ad_, denom);
  k_pA<<<dim3(CB, TT), 256, 0, stream>>>(ei, gcnt_d, gcnt_s);
  k_pB<<<TT * 2, 256, 0, stream>>>(gcnt_d, gcnt_s, goff_d, goff_s);
  k_pC<<<dim3(CB, TT), 256, 0, stream>>>(ei, goff_d, goff_s, part_d, part_s);
  k_denomB<<<dim3(NB, TT), 256, 0, stream>>>(part_d, goff_d, as_, ad_, denom);
  k_dinvaux<<<(TT * NNODES) / 256, 256, 0, stream>>>(denom, ad_, aux);
  k_starts<<<(NNODES + 255) / 256, 256, 0, stream>>>(batch, starts);
  k_cbuildB<<<dim3(NB, TT), 256, 0, stream>>>(part_s, goff_s, as_, aux, batch, cbuf);
  k_pgemm<<<TT * NCH, 256, 0, stream>>>(hbuf, cbuf, ppart);
  k_lstm_fc<<<BGR, 512, 0, stream>>>(ppart, starts, gat_bias, W_ih, W_hh, b_ih, b_hh, z, fc_W, fc_b, out);
}

// Round 15
// 245.863 us; speedup vs baseline: 1.3530x; 1.3530x over previous
//
#include <hip/hip_runtime.h>
#include <math.h>

#define TT 8
#define NNODES 20000
#define NEDGES 320000
#define FDIM 128
#define HDIM 128
#define BGR 64
#define NCLS 16
#define NCH 32    // K-chunks per timestep for k_pgemm
#define KC 640    // nodes per chunk
#define NB 157    // radix buckets of 128 nodes (157*128 = 20096 >= 20000)
#define CB 80     // edge chunks per timestep
#define EC 4000   // edges per chunk (80*4000 = 320000)

__device__ __forceinline__ float lrelu(float x) { return fmaxf(x, 0.2f * x); }
__device__ __forceinline__ float sigmoidf(float x) { return 1.0f / (1.0f + __expf(-x)); }
__device__ __forceinline__ float tanh_fast(float x) {
  return 1.0f - 2.0f / (__expf(2.0f * x) + 1.0f);
}
__device__ __forceinline__ unsigned short f2bf(float f) {   // RNE
  unsigned int u = __float_as_uint(f);
  unsigned int r = (u + 0x7fff + ((u >> 16) & 1)) >> 16;
  return (unsigned short)r;
}
__device__ __forceinline__ float bf_lo(unsigned int u) { return __uint_as_float(u << 16); }
__device__ __forceinline__ float bf_hi(unsigned int u) { return __uint_as_float(u & 0xffff0000u); }

// ---------------- prep: u = W@att_src, v = W@att_dst, wT = W^T (one block, one-time)
__global__ __launch_bounds__(256) void k_prep(
    const float* __restrict__ W, const float* __restrict__ att_s, const float* __restrict__ att_d,
    float* __restrict__ u, float* __restrict__ v, float* __restrict__ wT) {
  const int tid = threadIdx.x;
  for (int i = tid; i < 128 * 128; i += 256) {
    int k = i >> 7, n = i & 127;
    wT[n * 128 + k] = W[i];
  }
  if (tid < 128) {
    float su = 0.f, sv = 0.f;
    const float4* wr = (const float4*)(W + (size_t)tid * 128);
    #pragma unroll 8
    for (int q = 0; q < 32; ++q) {
      float4 w4 = wr[q];
      float4 a4 = *(const float4*)(att_s + q * 4);
      float4 d4 = *(const float4*)(att_d + q * 4);
      su += w4.x * a4.x + w4.y * a4.y + w4.z * a4.z + w4.w * a4.w;
      sv += w4.x * d4.x + w4.y * d4.y + w4.z * d4.z + w4.w * d4.w;
    }
    u[tid] = su; v[tid] = sv;
  }
}

// ---------------- GEMV: as = x@u, ad = x@v over all T*N rows; denom seed fused.
// 32 lanes per row (float4 each), fully coalesced; shfl-reduce within 32-lane group.
__global__ __launch_bounds__(256) void k_gemv(
    const float* __restrict__ x, const float* __restrict__ u, const float* __restrict__ v,
    float* __restrict__ as_, float* __restrict__ ad_, float* __restrict__ denom) {
  const int tid = threadIdx.x;
  const int c4 = tid & 31;
  const int ty = tid >> 5;           // 0..7: row within iteration
  const int lane = tid & 63;
  float4 uu = *(const float4*)(u + c4 * 4);
  float4 vv = *(const float4*)(v + c4 * 4);
  const int base = blockIdx.x * 64;
  #pragma unroll
  for (int it = 0; it < 8; ++it) {
    int r = base + it * 8 + ty;
    float4 xv = *(const float4*)(x + (size_t)r * FDIM + c4 * 4);
    float ps = xv.x * uu.x + xv.y * uu.y + xv.z * uu.z + xv.w * uu.w;
    float pd = xv.x * vv.x + xv.y * vv.y + xv.z * vv.z + xv.w * vv.w;
    #pragma unroll
    for (int o = 16; o > 0; o >>= 1) { ps += __shfl_xor(ps, o); pd += __shfl_xor(pd, o); }
    if ((lane & 31) == 0) {
      as_[r] = ps;
      ad_[r] = pd;
      denom[r] = __expf(lrelu(ps + pd));   // self-loop seeds denominator
    }
  }
}

// ---------------- radix pass A: per-(t,chunk) bucket histograms, keyed by dst AND src
__global__ __launch_bounds__(256) void k_pA(const int* __restrict__ ei,
                                            int* __restrict__ gcnt_d, int* __restrict__ gcnt_s) {
  __shared__ int hd[NB], hs[NB];
  const int tid = threadIdx.x;
  const int chunk = blockIdx.x, t = blockIdx.y;
  if (tid < NB) { hd[tid] = 0; hs[tid] = 0; }
  __syncthreads();
  const int* eis = ei + (size_t)t * 2 * NEDGES;
  for (int i = tid; i < EC; i += 256) {
    int e = chunk * EC + i;
    int s = eis[e], d = eis[NEDGES + e];
    atomicAdd(&hd[d >> 7], 1);
    atomicAdd(&hs[s >> 7], 1);
  }
  __syncthreads();
  if (tid < NB) {
    gcnt_d[((size_t)t * CB + chunk) * NB + tid] = hd[tid];
    gcnt_s[((size_t)t * CB + chunk) * NB + tid] = hs[tid];
  }
}

// ---------------- radix pass B: per-(t,axis) exclusive scan -> goff[t][bucket][chunk]
__global__ __launch_bounds__(256) void k_pB(const int* __restrict__ gcnt_d, const int* __restrict__ gcnt_s,
                                            int* __restrict__ goff_d, int* __restrict__ goff_s) {
  const int t = blockIdx.x >> 1, axis = blockIdx.x & 1;
  const int tid = threadIdx.x;
  const int* gc = axis ? gcnt_s : gcnt_d;
  int* go = axis ? goff_s : goff_d;
  __shared__ int tot[NB];
  __shared__ int base[NB];
  if (tid < NB) {
    int s = 0;
    for (int c = 0; c < CB; ++c) s += gc[((size_t)t * CB + c) * NB + tid];
    tot[tid] = s;
  }
  __syncthreads();
  if (tid == 0) {
    int run = 0;
    for (int B = 0; B < NB; ++B) { base[B] = run; run += tot[B]; }
  }
  __syncthreads();
  if (tid < NB) {
    int run = base[tid];
    for (int c = 0; c < CB; ++c) {
      go[((size_t)t * NB + tid) * CB + c] = run;
      run += gc[((size_t)t * CB + c) * NB + tid];
    }
  }
}

// ---------------- radix pass C: scatter packed records into both partitions (LDS cursors)
__global__ __launch_bounds__(256) void k_pC(const int* __restrict__ ei,
                                            const int* __restrict__ goff_d, const int* __restrict__ goff_s,
                                            unsigned int* __restrict__ part_d, unsigned int* __restrict__ part_s) {
  __shared__ int cd[NB], cs2[NB];
  const int tid = threadIdx.x;
  const int chunk = blockIdx.x, t = blockIdx.y;
  if (tid < NB) {
    cd[tid]  = goff_d[((size_t)t * NB + tid) * CB + chunk];
    cs2[tid] = goff_s[((size_t)t * NB + tid) * CB + chunk];
  }
  __syncthreads();
  const int* eis = ei + (size_t)t * 2 * NEDGES;
  unsigned int* pdt = part_d + (size_t)t * NEDGES;
  unsigned int* pst = part_s + (size_t)t * NEDGES;
  for (int i = tid; i < EC; i += 256) {
    int e = chunk * EC + i;
    int s = eis[e], d = eis[NEDGES + e];
    unsigned int rec = ((unsigned int)s << 15) | (unsigned int)d;
    int pd = atomicAdd(&cd[d >> 7], 1);
    pdt[pd] = rec;
    int ps = atomicAdd(&cs2[s >> 7], 1);
    pst[ps] = rec;
  }
}

// ---------------- denominator from dst-partition: LDS hist, plain-store flush
__global__ __launch_bounds__(256) void k_denomB(
    const unsigned int* __restrict__ part_d, const int* __restrict__ goff_d,
    const float* __restrict__ as_, const float* __restrict__ ad_, float* __restrict__ denom) {
  __shared__ float hist[128];
  __shared__ float adl[128];
  const int tid = threadIdx.x;
  const int B = blockIdx.x, t = blockIdx.y;
  if (tid < 128) {
    hist[tid] = 0.f;
    int n = B * 128 + tid;
    adl[tid] = (n < NNODES) ? ad_[t * NNODES + n] : 0.f;
  }
  __syncthreads();
  const int base = goff_d[((size_t)t * NB + B) * CB + 0];
  const int end  = (B + 1 < NB) ? goff_d[((size_t)t * NB + B + 1) * CB + 0] : NEDGES;
  const unsigned int* pdt = part_d + (size_t)t * NEDGES;
  const float* asb = as_ + (size_t)t * NNODES;
  for (int i = base + tid; i < end; i += 256) {
    unsigned int rec = pdt[i];
    int d = rec & 32767, s = rec >> 15;
    float w = __expf(lrelu(asb[s] + adl[d & 127]));
    atomicAdd(&hist[d & 127], w);
  }
  __syncthreads();
  if (tid < 128) {
    int n = B * 128 + tid;
    if (n < NNODES) denom[t * NNODES + n] += hist[tid];   // seed already there
  }
}

// ---------------- aux pack: (ad, 1/denom) per node
__global__ void k_dinvaux(const float* __restrict__ denom, const float* __restrict__ ad_,
                          float2* __restrict__ aux) {
  int i = blockIdx.x * 256 + threadIdx.x;   // 160000 / 256 = 625 exact
  aux[i] = make_float2(ad_[i], 1.0f / denom[i]);
}

// ---------------- batch segment starts (batch is sorted)
__global__ void k_starts(const int* __restrict__ batch, int* __restrict__ starts) {
  int n = blockIdx.x * 256 + threadIdx.x;
  if (n >= NNODES) return;
  int b = batch[n];
  if (n == 0) { for (int bb = 0; bb <= b; ++bb) starts[bb] = 0; }
  else { int pb = batch[n - 1]; for (int bb = pb + 1; bb <= b; ++bb) starts[bb] = n; }
  if (n == NNODES - 1) { for (int bb = b + 1; bb <= BGR; ++bb) starts[bb] = NNODES; }
}

// ---------------- c build from src-partition: LDS tile c_loc[64][128], plain-store flush
__global__ __launch_bounds__(256) void k_cbuildB(
    const unsigned int* __restrict__ part_s, const int* __restrict__ goff_s,
    const float* __restrict__ as_, const float2* __restrict__ aux,
    const int* __restrict__ batch, float* __restrict__ c) {
  __shared__ float cl[BGR * 128];   // 32 KB
  __shared__ float asl[128];
  const int tid = threadIdx.x;
  const int B = blockIdx.x, t = blockIdx.y;
  #pragma unroll
  for (int i = tid; i < BGR * 128; i += 256) cl[i] = 0.f;
  if (tid < 128) {
    int n = B * 128 + tid;
    asl[tid] = (n < NNODES) ? as_[t * NNODES + n] : 0.f;
  }
  __syncthreads();
  if (tid < 128) {   // self-loop coefficient
    int n = B * 128 + tid;
    if (n < NNODES) {
      float2 a2 = aux[t * NNODES + n];
      float wself = __expf(lrelu(asl[tid] + a2.x)) * a2.y;
      cl[batch[n] * 128 + tid] = wself;
    }
  }
  __syncthreads();
  const int base = goff_s[((size_t)t * NB + B) * CB + 0];
  const int end  = (B + 1 < NB) ? goff_s[((size_t)t * NB + B + 1) * CB + 0] : NEDGES;
  const unsigned int* pst = part_s + (size_t)t * NEDGES;
  const float2* auxt = aux + (size_t)t * NNODES;
  for (int i = base + tid; i < end; i += 256) {
    unsigned int rec = pst[i];
    int d = rec & 32767, s = rec >> 15;
    float2 a2 = auxt[d];
    float w = __expf(lrelu(asl[s & 127] + a2.x)) * a2.y;
    atomicAdd(&cl[batch[d] * 128 + (s & 127)], w);
  }
  __syncthreads();
  float* cb = c + (size_t)t * BGR * NNODES;
  #pragma unroll
  for (int idx = tid; idx < BGR * 128; idx += 256) {
    int b = idx >> 7, j = idx & 127;
    int col = B * 128 + j;
    if (col < NNODES) cb[(size_t)b * NNODES + col] = cl[idx];
  }
}

// ---------------- P = c @ x : per (t, K-chunk) block -> [64 x 128] fp32 partial.
// Split-col mapping (cols {dq*4..+3} U {64+dq*4..+3}) -> 2-way LDS bank groups (free).
__global__ __launch_bounds__(256) void k_pgemm(
    const float* __restrict__ x, const float* __restrict__ c,
    float* __restrict__ ppart) {
  __shared__ float cs[64][33];
  __shared__ float xs[32][132];
  const int tid = threadIdx.x;
  const int t = blockIdx.x >> 5;
  const int ch = blockIdx.x & (NCH - 1);
  const int k0 = ch * KC;
  const int k1 = min(k0 + KC, NNODES);
  const int bq = tid >> 4;
  const int dq = tid & 15;
  const float* cb = c + (size_t)t * BGR * NNODES;
  const float* xbase = x + (size_t)t * NNODES * FDIM;
  float acc[4][8] = {};
  for (int kt = k0; kt < k1; kt += 32) {
    __syncthreads();
    #pragma unroll
    for (int p = 0; p < 2; ++p) {       // stage c: 64 b x 32 k
      int idx = tid + p * 256;
      int b = idx >> 3, q = idx & 7;
      float4 v = *(const float4*)(cb + (size_t)b * NNODES + kt + q * 4);
      cs[b][q * 4 + 0] = v.x; cs[b][q * 4 + 1] = v.y;
      cs[b][q * 4 + 2] = v.z; cs[b][q * 4 + 3] = v.w;
    }
    #pragma unroll
    for (int p = 0; p < 4; ++p) {       // stage x: 32 k x 128 d fp32
      int idx = tid + p * 256;          // 0..1023
      int r = idx >> 5, c4 = (idx & 31) * 4;
      *(float4*)&xs[r][c4] = *(const float4*)(xbase + (size_t)(kt + r) * FDIM + c4);
    }
    __syncthreads();
    #pragma unroll
    for (int kk = 0; kk < 32; ++kk) {
      float cv[4];
      #pragma unroll
      for (int i = 0; i < 4; ++i) cv[i] = cs[bq * 4 + i][kk];
      float xd[8];
      *(float4*)&xd[0] = *(const float4*)&xs[kk][dq * 4];
      *(float4*)&xd[4] = *(const float4*)&xs[kk][64 + dq * 4];
      #pragma unroll
      for (int i = 0; i < 4; ++i)
        #pragma unroll
        for (int d = 0; d < 8; ++d)
          acc[i][d] += cv[i] * xd[d];
    }
  }
  float* pp = ppart + ((size_t)t * NCH + ch) * BGR * HDIM;
  #pragma unroll
  for (int i = 0; i < 4; ++i) {
    *(float4*)(pp + (bq * 4 + i) * HDIM + dq * 4)      = make_float4(acc[i][0], acc[i][1], acc[i][2], acc[i][3]);
    *(float4*)(pp + (bq * 4 + i) * HDIM + 64 + dq * 4) = make_float4(acc[i][4], acc[i][5], acc[i][6], acc[i][7]);
  }
}

// ---------------- pooled = (sum_ch P) @ W * invc + gat_bias  (block per (t,b))
__global__ __launch_bounds__(128) void k_pw(
    const float* __restrict__ ppart, const int* __restrict__ starts,
    const float* __restrict__ wT, const float* __restrict__ gat_bias,
    float* __restrict__ pooled) {
  __shared__ float srow[128];
  const int tb = blockIdx.x;       // 0..511
  const int t = tb >> 6, b = tb & 63;
  const int d = threadIdx.x;
  float s = 0.f;
  const float* pp = ppart + ((size_t)t * NCH * BGR + b) * HDIM + d;
  #pragma unroll 8
  for (int ch = 0; ch < NCH; ++ch) s += pp[(size_t)ch * BGR * HDIM];
  srow[d] = s;
  __syncthreads();
  const float invc = 1.0f / (float)max(starts[b + 1] - starts[b], 1);
  float o = 0.f;
  const float4* wr = (const float4*)(wT + (size_t)d * 128);
  const float4* sr = (const float4*)srow;
  #pragma unroll 8
  for (int q = 0; q < 32; ++q) {
    float4 w4 = wr[q], s4 = sr[q];
    o += w4.x * s4.x + w4.y * s4.y + w4.z * s4.z + w4.w * s4.w;
  }
  pooled[(size_t)(t * BGR + b) * HDIM + d] = o * invc + gat_bias[d];
}

// ---------------- LSTM over T + fused FC (one block per batch row b)
__global__ __launch_bounds__(512) void k_lstm_fc(
    const float* __restrict__ pooled,
    const float* __restrict__ W_ih, const float* __restrict__ W_hh,
    const float* __restrict__ b_ih, const float* __restrict__ b_hh,
    const float* __restrict__ z, const float* __restrict__ fc_W,
    const float* __restrict__ fc_b, float* __restrict__ out) {
  const int b = blockIdx.x;
  const int g = threadIdx.x;
  __shared__ unsigned int wpk[512 * 65];
  __shared__ float hv[128], cv[128], part[512];
  __shared__ float pool8[TT][128];
  __shared__ float fcp[16][17];

  #pragma unroll 2
  for (int it = 0; it < 64; ++it) {
    int i = g + it * 512;
    int gr = i >> 6, j = i & 63;
    float2 wv = *(const float2*)(W_hh + (size_t)gr * HDIM + j * 2);
    wpk[gr * 65 + j] = (unsigned int)f2bf(wv.x) | ((unsigned int)f2bf(wv.y) << 16);
  }
  #pragma unroll
  for (int i = 0; i < 2; ++i) {
    int idx = g + i * 512;
    int t = idx >> 7, k = idx & 127;
    pool8[t][k] = pooled[((size_t)t * BGR + b) * HDIM + k];
  }
  if (g < 128) { hv[g] = 0.f; cv[g] = 0.f; }
  __syncthreads();

  float gx[8] = {};
  {
    const float4* wi = (const float4*)(W_ih + (size_t)g * HDIM);
    #pragma unroll 2
    for (int k4 = 0; k4 < 32; ++k4) {
      float4 wv = wi[k4];
      #pragma unroll
      for (int t = 0; t < TT; ++t) {
        float4 p = *(const float4*)(&pool8[t][k4 * 4]);
        gx[t] += wv.x * p.x + wv.y * p.y + wv.z * p.z + wv.w * p.w;
      }
    }
  }
  const float bsum = b_ih[g] + b_hh[g];
  const unsigned int* wr = &wpk[g * 65];
  const float4* hv4 = (const float4*)hv;
  #pragma unroll
  for (int t = 0; t < TT; ++t) {
    float s = gx[t] + bsum;
    #pragma unroll 8
    for (int j2 = 0; j2 < 32; ++j2) {
      unsigned int w0 = wr[2 * j2], w1 = wr[2 * j2 + 1];
      float4 hh = hv4[j2];
      s += bf_lo(w0) * hh.x + bf_hi(w0) * hh.y + bf_lo(w1) * hh.z + bf_hi(w1) * hh.w;
    }
    part[g] = s;
    __syncthreads();
    if (g < 128) {
      float ig = sigmoidf(part[g]);
      float fg = sigmoidf(part[128 + g]);
      float gc = tanh_fast(part[256 + g]);
      float og = sigmoidf(part[384 + g]);
      float c = fg * cv[g] + ig * gc;
      cv[g] = c;
      hv[g] = og * tanh_fast(c);
    }
    __syncthreads();
  }
  if (g < 256) {
    const int c = g >> 4, kp = g & 15;
    float s = 0.f;
    for (int k = kp * 16; k < kp * 16 + 16; ++k) {
      float v = (k < 128) ? hv[k] : z[(size_t)b * HDIM + (k - 128)];
      s += v * fc_W[(size_t)c * 256 + k];
    }
    fcp[c][kp] = s;
  }
  __syncthreads();
  if (g < 16) {
    float r = fc_b[g];
    #pragma unroll
    for (int k = 0; k < 16; ++k) r += fcp[g][k];
    out[(size_t)b * NCLS + g] = r;
  }
}

extern "C" void kernel_launch(void* const* d_in, const int* in_sizes, int n_in,
                              void* d_out, int out_size, void* d_ws, size_t ws_size,
                              hipStream_t stream) {
  const float* x       = (const float*)d_in[0];
  const int*   ei      = (const int*)d_in[1];
  const int*   batch   = (const int*)d_in[2];
  const float* z       = (const float*)d_in[3];
  const float* gat_W   = (const float*)d_in[4];
  const float* att_src = (const float*)d_in[5];
  const float* att_dst = (const float*)d_in[6];
  const float* gat_bias= (const float*)d_in[7];
  const float* W_ih    = (const float*)d_in[8];
  const float* W_hh    = (const float*)d_in[9];
  const float* b_ih    = (const float*)d_in[10];
  const float* b_hh    = (const float*)d_in[11];
  const float* fc_W    = (const float*)d_in[12];
  const float* fc_b    = (const float*)d_in[13];
  float* out = (float*)d_out;

  char* ws = (char*)d_ws;
  size_t off = 0;
  auto alloc = [&](size_t bytes) {
    void* p = (void*)(ws + off);
    off += (bytes + 255) & ~(size_t)255;
    return p;
  };
  float*  as_    = (float*)alloc((size_t)TT * NNODES * 4);
  float*  ad_    = (float*)alloc((size_t)TT * NNODES * 4);
  float*  denom  = (float*)alloc((size_t)TT * NNODES * 4);
  float2* aux    = (float2*)alloc((size_t)TT * NNODES * 8);
  float*  cbuf   = (float*)alloc((size_t)TT * BGR * NNODES * 4);                  // 40.96 MB
  // partition region; ppart aliases its start (parts dead before k_pgemm writes)
  size_t parts_off = off;
  unsigned int* part_d = (unsigned int*)alloc((size_t)TT * NEDGES * 4);           // 10.24 MB
  unsigned int* part_s = (unsigned int*)alloc((size_t)TT * NEDGES * 4);           // 10.24 MB
  float* ppart = (float*)(ws + parts_off);                                        // 8.39 MB alias
  int* gcnt_d = (int*)alloc((size_t)TT * CB * NB * 4);
  int* gcnt_s = (int*)alloc((size_t)TT * CB * NB * 4);
  int* goff_d = (int*)alloc((size_t)TT * NB * CB * 4);
  int* goff_s = (int*)alloc((size_t)TT * NB * CB * 4);
  float* uvec  = (float*)alloc(128 * 4);
  float* vvec  = (float*)alloc(128 * 4);
  float* wTbuf = (float*)alloc(128 * 128 * 4);
  float* pooled = (float*)alloc((size_t)TT * BGR * HDIM * 4);
  int* starts = (int*)alloc((BGR + 1) * 4);
  (void)ws_size; (void)in_sizes; (void)n_in; (void)out_size;

  k_prep<<<1, 256, 0, stream>>>(gat_W, att_src, att_dst, uvec, vvec, wTbuf);
  k_gemv<<<(TT * NNODES) / 64, 256, 0, stream>>>(x, uvec, vvec, as_, ad_, denom);
  k_pA<<<dim3(CB, TT), 256, 0, stream>>>(ei, gcnt_d, gcnt_s);
  k_pB<<<TT * 2, 256, 0, stream>>>(gcnt_d, gcnt_s, goff_d, goff_s);
  k_pC<<<dim3(CB, TT), 256, 0, stream>>>(ei, goff_d, goff_s, part_d, part_s);
  k_denomB<<<dim3(NB, TT), 256, 0, stream>>>(part_d, goff_d, as_, ad_, denom);
  k_dinvaux<<<(TT * NNODES) / 256, 256, 0, stream>>>(denom, ad_, aux);
  k_starts<<<(NNODES + 255) / 256, 256, 0, stream>>>(batch, starts);
  k_cbuildB<<<dim3(NB, TT), 256, 0, stream>>>(part_s, goff_s, as_, aux, batch, cbuf);
  k_pgemm<<<TT * NCH, 256, 0, stream>>>(x, cbuf, ppart);
  k_pw<<<TT * BGR, 128, 0, stream>>>(ppart, starts, wTbuf, gat_bias, pooled);
  k_lstm_fc<<<BGR, 512, 0, stream>>>(pooled, W_ih, W_hh, b_ih, b_hh, z, fc_W, fc_b, out);
}

// Round 16
// 234.595 us; speedup vs baseline: 1.4180x; 1.0480x over previous
//
#include <hip/hip_runtime.h>
#include <math.h>

#define TT 8
#define NNODES 20000
#define NEDGES 320000
#define FDIM 128
#define HDIM 128
#define BGR 64
#define NCLS 16
#define NB 157    // radix buckets of 128 nodes (157*128 = 20096 >= 20000)
#define CB 80     // edge chunks per timestep
#define EC 4000   // edges per chunk (80*4000 = 320000)
#define CLS 132   // c-tile LDS row stride (floats)

__device__ __forceinline__ float lrelu(float x) { return fmaxf(x, 0.2f * x); }
__device__ __forceinline__ float sigmoidf(float x) { return 1.0f / (1.0f + __expf(-x)); }
__device__ __forceinline__ float tanh_fast(float x) {
  return 1.0f - 2.0f / (__expf(2.0f * x) + 1.0f);
}
__device__ __forceinline__ unsigned short f2bf(float f) {   // RNE
  unsigned int u = __float_as_uint(f);
  unsigned int r = (u + 0x7fff + ((u >> 16) & 1)) >> 16;
  return (unsigned short)r;
}
__device__ __forceinline__ float bf_lo(unsigned int u) { return __uint_as_float(u << 16); }
__device__ __forceinline__ float bf_hi(unsigned int u) { return __uint_as_float(u & 0xffff0000u); }

// ---------------- prep: u = W@att_src, v = W@att_dst, wT = W^T (one block, one-time)
__global__ __launch_bounds__(256) void k_prep(
    const float* __restrict__ W, const float* __restrict__ att_s, const float* __restrict__ att_d,
    float* __restrict__ u, float* __restrict__ v, float* __restrict__ wT) {
  const int tid = threadIdx.x;
  for (int i = tid; i < 128 * 128; i += 256) {
    int k = i >> 7, n = i & 127;
    wT[n * 128 + k] = W[i];
  }
  if (tid < 128) {
    float su = 0.f, sv = 0.f;
    const float4* wr = (const float4*)(W + (size_t)tid * 128);
    #pragma unroll 8
    for (int q = 0; q < 32; ++q) {
      float4 w4 = wr[q];
      float4 a4 = *(const float4*)(att_s + q * 4);
      float4 d4 = *(const float4*)(att_d + q * 4);
      su += w4.x * a4.x + w4.y * a4.y + w4.z * a4.z + w4.w * a4.w;
      sv += w4.x * d4.x + w4.y * d4.y + w4.z * d4.z + w4.w * d4.w;
    }
    u[tid] = su; v[tid] = sv;
  }
}

// ---------------- GEMV: as = x@u, ad = x@v over all T*N rows; denom seed fused.
__global__ __launch_bounds__(256) void k_gemv(
    const float* __restrict__ x, const float* __restrict__ u, const float* __restrict__ v,
    float* __restrict__ as_, float* __restrict__ ad_, float* __restrict__ denom) {
  const int tid = threadIdx.x;
  const int c4 = tid & 31;
  const int ty = tid >> 5;           // 0..7: row within iteration
  const int lane = tid & 63;
  float4 uu = *(const float4*)(u + c4 * 4);
  float4 vv = *(const float4*)(v + c4 * 4);
  const int base = blockIdx.x * 64;
  #pragma unroll
  for (int it = 0; it < 8; ++it) {
    int r = base + it * 8 + ty;
    float4 xv = *(const float4*)(x + (size_t)r * FDIM + c4 * 4);
    float ps = xv.x * uu.x + xv.y * uu.y + xv.z * uu.z + xv.w * uu.w;
    float pd = xv.x * vv.x + xv.y * vv.y + xv.z * vv.z + xv.w * vv.w;
    #pragma unroll
    for (int o = 16; o > 0; o >>= 1) { ps += __shfl_xor(ps, o); pd += __shfl_xor(pd, o); }
    if ((lane & 31) == 0) {
      as_[r] = ps;
      ad_[r] = pd;
      denom[r] = __expf(lrelu(ps + pd));   // self-loop seeds denominator
    }
  }
}

// ---------------- radix pass A: per-(t,chunk) bucket histograms, keyed by dst AND src
__global__ __launch_bounds__(256) void k_pA(const int* __restrict__ ei,
                                            int* __restrict__ gcnt_d, int* __restrict__ gcnt_s) {
  __shared__ int hd[NB], hs[NB];
  const int tid = threadIdx.x;
  const int chunk = blockIdx.x, t = blockIdx.y;
  if (tid < NB) { hd[tid] = 0; hs[tid] = 0; }
  __syncthreads();
  const int* eis = ei + (size_t)t * 2 * NEDGES;
  for (int i = tid; i < EC; i += 256) {
    int e = chunk * EC + i;
    int s = eis[e], d = eis[NEDGES + e];
    atomicAdd(&hd[d >> 7], 1);
    atomicAdd(&hs[s >> 7], 1);
  }
  __syncthreads();
  if (tid < NB) {
    gcnt_d[((size_t)t * CB + chunk) * NB + tid] = hd[tid];
    gcnt_s[((size_t)t * CB + chunk) * NB + tid] = hs[tid];
  }
}

// ---------------- radix pass B: per-(t,axis) exclusive scan -> goff[t][bucket][chunk]
__global__ __launch_bounds__(256) void k_pB(const int* __restrict__ gcnt_d, const int* __restrict__ gcnt_s,
                                            int* __restrict__ goff_d, int* __restrict__ goff_s) {
  const int t = blockIdx.x >> 1, axis = blockIdx.x & 1;
  const int tid = threadIdx.x;
  const int* gc = axis ? gcnt_s : gcnt_d;
  int* go = axis ? goff_s : goff_d;
  __shared__ int tot[NB];
  __shared__ int base[NB];
  if (tid < NB) {
    int s = 0;
    for (int c = 0; c < CB; ++c) s += gc[((size_t)t * CB + c) * NB + tid];
    tot[tid] = s;
  }
  __syncthreads();
  if (tid == 0) {
    int run = 0;
    for (int B = 0; B < NB; ++B) { base[B] = run; run += tot[B]; }
  }
  __syncthreads();
  if (tid < NB) {
    int run = base[tid];
    for (int c = 0; c < CB; ++c) {
      go[((size_t)t * NB + tid) * CB + c] = run;
      run += gc[((size_t)t * CB + c) * NB + tid];
    }
  }
}

// ---------------- radix pass C: scatter packed records into both partitions (LDS cursors)
__global__ __launch_bounds__(256) void k_pC(const int* __restrict__ ei,
                                            const int* __restrict__ goff_d, const int* __restrict__ goff_s,
                                            unsigned int* __restrict__ part_d, unsigned int* __restrict__ part_s) {
  __shared__ int cd[NB], cs2[NB];
  const int tid = threadIdx.x;
  const int chunk = blockIdx.x, t = blockIdx.y;
  if (tid < NB) {
    cd[tid]  = goff_d[((size_t)t * NB + tid) * CB + chunk];
    cs2[tid] = goff_s[((size_t)t * NB + tid) * CB + chunk];
  }
  __syncthreads();
  const int* eis = ei + (size_t)t * 2 * NEDGES;
  unsigned int* pdt = part_d + (size_t)t * NEDGES;
  unsigned int* pst = part_s + (size_t)t * NEDGES;
  for (int i = tid; i < EC; i += 256) {
    int e = chunk * EC + i;
    int s = eis[e], d = eis[NEDGES + e];
    unsigned int rec = ((unsigned int)s << 15) | (unsigned int)d;
    int pd = atomicAdd(&cd[d >> 7], 1);
    pdt[pd] = rec;
    int ps = atomicAdd(&cs2[s >> 7], 1);
    pst[ps] = rec;
  }
}

// ---------------- denominator from dst-partition; aux=(ad,1/denom) fused here
__global__ __launch_bounds__(256) void k_denomB(
    const unsigned int* __restrict__ part_d, const int* __restrict__ goff_d,
    const float* __restrict__ as_, const float* __restrict__ ad_,
    const float* __restrict__ dseed, float2* __restrict__ aux) {
  __shared__ float hist[128];
  __shared__ float adl[128];
  const int tid = threadIdx.x;
  const int B = blockIdx.x, t = blockIdx.y;
  if (tid < 128) {
    hist[tid] = 0.f;
    int n = B * 128 + tid;
    adl[tid] = (n < NNODES) ? ad_[t * NNODES + n] : 0.f;
  }
  __syncthreads();
  const int base = goff_d[((size_t)t * NB + B) * CB + 0];
  const int end  = (B + 1 < NB) ? goff_d[((size_t)t * NB + B + 1) * CB + 0] : NEDGES;
  const unsigned int* pdt = part_d + (size_t)t * NEDGES;
  const float* asb = as_ + (size_t)t * NNODES;
  for (int i = base + tid; i < end; i += 256) {
    unsigned int rec = pdt[i];
    int d = rec & 32767, s = rec >> 15;
    float w = __expf(lrelu(asb[s] + adl[d & 127]));
    atomicAdd(&hist[d & 127], w);
  }
  __syncthreads();
  if (tid < 128) {
    int n = B * 128 + tid;
    if (n < NNODES) {
      float den = dseed[t * NNODES + n] + hist[tid];
      aux[t * NNODES + n] = make_float2(adl[tid], 1.0f / den);
    }
  }
}

// ---------------- batch segment starts (batch is sorted)
__global__ void k_starts(const int* __restrict__ batch, int* __restrict__ starts) {
  int n = blockIdx.x * 256 + threadIdx.x;
  if (n >= NNODES) return;
  int b = batch[n];
  if (n == 0) { for (int bb = 0; bb <= b; ++bb) starts[bb] = 0; }
  else { int pb = batch[n - 1]; for (int bb = pb + 1; bb <= b; ++bb) starts[bb] = n; }
  if (n == NNODES - 1) { for (int bb = b + 1; bb <= BGR; ++bb) starts[bb] = NNODES; }
}

// ---------------- FUSED c-build + P-partial: per (t, src-bucket B) block.
// Phase 1 (= old k_cbuildB): build c_loc[64][CLS] in LDS from self-loops +
//   src-partition edges (LDS atomics; never leaves LDS).
// Phase 2 (= old k_pgemm): partial[64 b][128 d] = c_loc @ x[bucket rows],
//   x staged 32 rows at a time; OOB rows clamped (their c_loc coeffs are 0).
// Grid = 157*8 = 1256 blocks (~5/CU vs old pgemm's 1/CU).
__global__ __launch_bounds__(256) void k_cpgemm(
    const unsigned int* __restrict__ part_s, const int* __restrict__ goff_s,
    const float* __restrict__ as_, const float2* __restrict__ aux,
    const int* __restrict__ batch, const float* __restrict__ x,
    float* __restrict__ ppart) {
  __shared__ float cl[BGR * CLS];   // 33.8 KB
  __shared__ float asl[128];
  __shared__ float xs[32][CLS];     // 16.9 KB
  const int tid = threadIdx.x;
  const int B = blockIdx.x, t = blockIdx.y;
  #pragma unroll
  for (int i = tid; i < BGR * CLS; i += 256) cl[i] = 0.f;
  if (tid < 128) {
    int n = B * 128 + tid;
    asl[tid] = (n < NNODES) ? as_[t * NNODES + n] : 0.f;
  }
  __syncthreads();
  if (tid < 128) {   // self-loop coefficient
    int n = B * 128 + tid;
    if (n < NNODES) {
      float2 a2 = aux[t * NNODES + n];
      float wself = __expf(lrelu(asl[tid] + a2.x)) * a2.y;
      cl[batch[n] * CLS + tid] = wself;
    }
  }
  __syncthreads();
  {
    const int base = goff_s[((size_t)t * NB + B) * CB + 0];
    const int end  = (B + 1 < NB) ? goff_s[((size_t)t * NB + B + 1) * CB + 0] : NEDGES;
    const unsigned int* pst = part_s + (size_t)t * NEDGES;
    const float2* auxt = aux + (size_t)t * NNODES;
    for (int i = base + tid; i < end; i += 256) {
      unsigned int rec = pst[i];
      int d = rec & 32767, s = rec >> 15;
      float2 a2 = auxt[d];
      float w = __expf(lrelu(asl[s & 127] + a2.x)) * a2.y;
      atomicAdd(&cl[batch[d] * CLS + (s & 127)], w);
    }
  }
  // phase 2: [64 x 128] = cl[64 x 128k] @ x[128k x 128d]
  const int bq = tid >> 4;   // 4 b-rows each
  const int dq = tid & 15;   // cols {dq*4..+3} U {64+dq*4..+3} (2-way banks, free)
  const float* xbase = x + (size_t)t * NNODES * FDIM;
  float acc[4][8] = {};
  #pragma unroll
  for (int kt = 0; kt < 128; kt += 32) {
    __syncthreads();
    #pragma unroll
    for (int p = 0; p < 4; ++p) {       // stage x: 32 bucket rows x 128 d
      int idx = tid + p * 256;          // 0..1023
      int r = idx >> 5, c4 = (idx & 31) * 4;
      int row = B * 128 + kt + r;
      row = (row < NNODES) ? row : (NNODES - 1);   // clamp: cl coeff is 0 there
      *(float4*)&xs[r][c4] = *(const float4*)(xbase + (size_t)row * FDIM + c4);
    }
    __syncthreads();
    #pragma unroll
    for (int kk = 0; kk < 32; ++kk) {
      float cv[4];
      #pragma unroll
      for (int i = 0; i < 4; ++i) cv[i] = cl[(bq * 4 + i) * CLS + kt + kk];
      float xd[8];
      *(float4*)&xd[0] = *(const float4*)&xs[kk][dq * 4];
      *(float4*)&xd[4] = *(const float4*)&xs[kk][64 + dq * 4];
      #pragma unroll
      for (int i = 0; i < 4; ++i)
        #pragma unroll
        for (int d = 0; d < 8; ++d)
          acc[i][d] += cv[i] * xd[d];
    }
  }
  float* pp = ppart + ((size_t)t * NB + B) * BGR * HDIM;
  #pragma unroll
  for (int i = 0; i < 4; ++i) {
    *(float4*)(pp + (bq * 4 + i) * HDIM + dq * 4)      = make_float4(acc[i][0], acc[i][1], acc[i][2], acc[i][3]);
    *(float4*)(pp + (bq * 4 + i) * HDIM + 64 + dq * 4) = make_float4(acc[i][4], acc[i][5], acc[i][6], acc[i][7]);
  }
}

// ---------------- pooled = (sum_B P) @ W * invc + gat_bias  (block per (t,b))
__global__ __launch_bounds__(128) void k_pw(
    const float* __restrict__ ppart, const int* __restrict__ starts,
    const float* __restrict__ wT, const float* __restrict__ gat_bias,
    float* __restrict__ pooled) {
  __shared__ float srow[128];
  const int tb = blockIdx.x;       // 0..511
  const int t = tb >> 6, b = tb & 63;
  const int d = threadIdx.x;
  float s = 0.f;
  const float* pp = ppart + ((size_t)t * NB * BGR + b) * HDIM + d;
  #pragma unroll 4
  for (int B = 0; B < NB; ++B) s += pp[(size_t)B * BGR * HDIM];
  srow[d] = s;
  __syncthreads();
  const float invc = 1.0f / (float)max(starts[b + 1] - starts[b], 1);
  float o = 0.f;
  const float4* wr = (const float4*)(wT + (size_t)d * 128);
  const float4* sr = (const float4*)srow;
  #pragma unroll 8
  for (int q = 0; q < 32; ++q) {
    float4 w4 = wr[q], s4 = sr[q];
    o += w4.x * s4.x + w4.y * s4.y + w4.z * s4.z + w4.w * s4.w;
  }
  pooled[(size_t)(t * BGR + b) * HDIM + d] = o * invc + gat_bias[d];
}

// ---------------- LSTM over T + fused FC (one block per batch row b)
__global__ __launch_bounds__(512) void k_lstm_fc(
    const float* __restrict__ pooled,
    const float* __restrict__ W_ih, const float* __restrict__ W_hh,
    const float* __restrict__ b_ih, const float* __restrict__ b_hh,
    const float* __restrict__ z, const float* __restrict__ fc_W,
    const float* __restrict__ fc_b, float* __restrict__ out) {
  const int b = blockIdx.x;
  const int g = threadIdx.x;
  __shared__ unsigned int wpk[512 * 65];
  __shared__ float hv[128], cv[128], part[512];
  __shared__ float pool8[TT][128];
  __shared__ float fcp[16][17];

  #pragma unroll 2
  for (int it = 0; it < 64; ++it) {
    int i = g + it * 512;
    int gr = i >> 6, j = i & 63;
    float2 wv = *(const float2*)(W_hh + (size_t)gr * HDIM + j * 2);
    wpk[gr * 65 + j] = (unsigned int)f2bf(wv.x) | ((unsigned int)f2bf(wv.y) << 16);
  }
  #pragma unroll
  for (int i = 0; i < 2; ++i) {
    int idx = g + i * 512;
    int t = idx >> 7, k = idx & 127;
    pool8[t][k] = pooled[((size_t)t * BGR + b) * HDIM + k];
  }
  if (g < 128) { hv[g] = 0.f; cv[g] = 0.f; }
  __syncthreads();

  float gx[8] = {};
  {
    const float4* wi = (const float4*)(W_ih + (size_t)g * HDIM);
    #pragma unroll 2
    for (int k4 = 0; k4 < 32; ++k4) {
      float4 wv = wi[k4];
      #pragma unroll
      for (int t = 0; t < TT; ++t) {
        float4 p = *(const float4*)(&pool8[t][k4 * 4]);
        gx[t] += wv.x * p.x + wv.y * p.y + wv.z * p.z + wv.w * p.w;
      }
    }
  }
  const float bsum = b_ih[g] + b_hh[g];
  const unsigned int* wr = &wpk[g * 65];
  const float4* hv4 = (const float4*)hv;
  #pragma unroll
  for (int t = 0; t < TT; ++t) {
    float s = gx[t] + bsum;
    #pragma unroll 8
    for (int j2 = 0; j2 < 32; ++j2) {
      unsigned int w0 = wr[2 * j2], w1 = wr[2 * j2 + 1];
      float4 hh = hv4[j2];
      s += bf_lo(w0) * hh.x + bf_hi(w0) * hh.y + bf_lo(w1) * hh.z + bf_hi(w1) * hh.w;
    }
    part[g] = s;
    __syncthreads();
    if (g < 128) {
      float ig = sigmoidf(part[g]);
      float fg = sigmoidf(part[128 + g]);
      float gc = tanh_fast(part[256 + g]);
      float og = sigmoidf(part[384 + g]);
      float c = fg * cv[g] + ig * gc;
      cv[g] = c;
      hv[g] = og * tanh_fast(c);
    }
    __syncthreads();
  }
  if (g < 256) {
    const int c = g >> 4, kp = g & 15;
    float s = 0.f;
    for (int k = kp * 16; k < kp * 16 + 16; ++k) {
      float v = (k < 128) ? hv[k] : z[(size_t)b * HDIM + (k - 128)];
      s += v * fc_W[(size_t)c * 256 + k];
    }
    fcp[c][kp] = s;
  }
  __syncthreads();
  if (g < 16) {
    float r = fc_b[g];
    #pragma unroll
    for (int k = 0; k < 16; ++k) r += fcp[g][k];
    out[(size_t)b * NCLS + g] = r;
  }
}

extern "C" void kernel_launch(void* const* d_in, const int* in_sizes, int n_in,
                              void* d_out, int out_size, void* d_ws, size_t ws_size,
                              hipStream_t stream) {
  const float* x       = (const float*)d_in[0];
  const int*   ei      = (const int*)d_in[1];
  const int*   batch   = (const int*)d_in[2];
  const float* z       = (const float*)d_in[3];
  const float* gat_W   = (const float*)d_in[4];
  const float* att_src = (const float*)d_in[5];
  const float* att_dst = (const float*)d_in[6];
  const float* gat_bias= (const float*)d_in[7];
  const float* W_ih    = (const float*)d_in[8];
  const float* W_hh    = (const float*)d_in[9];
  const float* b_ih    = (const float*)d_in[10];
  const float* b_hh    = (const float*)d_in[11];
  const float* fc_W    = (const float*)d_in[12];
  const float* fc_b    = (const float*)d_in[13];
  float* out = (float*)d_out;

  char* ws = (char*)d_ws;
  size_t off = 0;
  auto alloc = [&](size_t bytes) {
    void* p = (void*)(ws + off);
    off += (bytes + 255) & ~(size_t)255;
    return p;
  };
  float*  as_    = (float*)alloc((size_t)TT * NNODES * 4);
  float*  ad_    = (float*)alloc((size_t)TT * NNODES * 4);
  float*  denom  = (float*)alloc((size_t)TT * NNODES * 4);
  float2* aux    = (float2*)alloc((size_t)TT * NNODES * 8);
  unsigned int* part_d = (unsigned int*)alloc((size_t)TT * NEDGES * 4);           // 10.24 MB
  unsigned int* part_s = (unsigned int*)alloc((size_t)TT * NEDGES * 4);           // 10.24 MB
  float* ppart = (float*)alloc((size_t)TT * NB * BGR * HDIM * 4);                 // 41.2 MB
  int* gcnt_d = (int*)alloc((size_t)TT * CB * NB * 4);
  int* gcnt_s = (int*)alloc((size_t)TT * CB * NB * 4);
  int* goff_d = (int*)alloc((size_t)TT * NB * CB * 4);
  int* goff_s = (int*)alloc((size_t)TT * NB * CB * 4);
  float* uvec  = (float*)alloc(128 * 4);
  float* vvec  = (float*)alloc(128 * 4);
  float* wTbuf = (float*)alloc(128 * 128 * 4);
  float* pooled = (float*)alloc((size_t)TT * BGR * HDIM * 4);
  int* starts = (int*)alloc((BGR + 1) * 4);
  (void)ws_size; (void)in_sizes; (void)n_in; (void)out_size;

  k_prep<<<1, 256, 0, stream>>>(gat_W, att_src, att_dst, uvec, vvec, wTbuf);
  k_gemv<<<(TT * NNODES) / 64, 256, 0, stream>>>(x, uvec, vvec, as_, ad_, denom);
  k_pA<<<dim3(CB, TT), 256, 0, stream>>>(ei, gcnt_d, gcnt_s);
  k_pB<<<TT * 2, 256, 0, stream>>>(gcnt_d, gcnt_s, goff_d, goff_s);
  k_pC<<<dim3(CB, TT), 256, 0, stream>>>(ei, goff_d, goff_s, part_d, part_s);
  k_denomB<<<dim3(NB, TT), 256, 0, stream>>>(part_d, goff_d, as_, ad_, denom, aux);
  k_starts<<<(NNODES + 255) / 256, 256, 0, stream>>>(batch, starts);
  k_cpgemm<<<dim3(NB, TT), 256, 0, stream>>>(part_s, goff_s, as_, aux, batch, x, ppart);
  k_pw<<<TT * BGR, 128, 0, stream>>>(ppart, starts, wTbuf, gat_bias, pooled);
  k_lstm_fc<<<BGR, 512, 0, stream>>>(pooled, W_ih, W_hh, b_ih, b_hh, z, fc_W, fc_b, out);
}

// Round 17
// 213.384 us; speedup vs baseline: 1.5589x; 1.0994x over previous
//
#include <hip/hip_runtime.h>
#include <math.h>

#define TT 8
#define NNODES 20000
#define NEDGES 320000
#define FDIM 128
#define HDIM 128
#define BGR 64
#define NCLS 16
#define NB 157    // radix buckets of 128 nodes (157*128 = 20096 >= 20000)
#define CB 80     // edge chunks per timestep
#define EC 4000   // edges per chunk (80*4000 = 320000)
#define CAP 2816  // bucket region capacity (mean 2038, sigma~45 -> +17 sigma)
#define CLSC 133  // c-tile LDS row stride (odd -> 16 bq-addresses on 16 banks, 2-way free)
#define XLS 132   // x-tile LDS row stride (mult of 4 for float4)

__device__ __forceinline__ float lrelu(float x) { return fmaxf(x, 0.2f * x); }
__device__ __forceinline__ float sigmoidf(float x) { return 1.0f / (1.0f + __expf(-x)); }
__device__ __forceinline__ float tanh_fast(float x) {
  return 1.0f - 2.0f / (__expf(2.0f * x) + 1.0f);
}
__device__ __forceinline__ unsigned short f2bf(float f) {   // RNE
  unsigned int u = __float_as_uint(f);
  unsigned int r = (u + 0x7fff + ((u >> 16) & 1)) >> 16;
  return (unsigned short)r;
}
__device__ __forceinline__ float bf_lo(unsigned int u) { return __uint_as_float(u << 16); }
__device__ __forceinline__ float bf_hi(unsigned int u) { return __uint_as_float(u & 0xffff0000u); }

// ---------------- prep: u = W@att_src, v = W@att_dst (one block, one-time)
__global__ __launch_bounds__(256) void k_prep(
    const float* __restrict__ W, const float* __restrict__ att_s, const float* __restrict__ att_d,
    float* __restrict__ u, float* __restrict__ v) {
  const int tid = threadIdx.x;
  if (tid < 128) {
    float su = 0.f, sv = 0.f;
    const float4* wr = (const float4*)(W + (size_t)tid * 128);
    #pragma unroll 8
    for (int q = 0; q < 32; ++q) {
      float4 w4 = wr[q];
      float4 a4 = *(const float4*)(att_s + q * 4);
      float4 d4 = *(const float4*)(att_d + q * 4);
      su += w4.x * a4.x + w4.y * a4.y + w4.z * a4.z + w4.w * a4.w;
      sv += w4.x * d4.x + w4.y * d4.y + w4.z * d4.z + w4.w * d4.w;
    }
    u[tid] = su; v[tid] = sv;
  }
}

// ---------------- GEMV: as = x@u, ad = x@v over all T*N rows; denom seed fused.
__global__ __launch_bounds__(256) void k_gemv(
    const float* __restrict__ x, const float* __restrict__ u, const float* __restrict__ v,
    float* __restrict__ as_, float* __restrict__ ad_, float* __restrict__ denom) {
  const int tid = threadIdx.x;
  const int c4 = tid & 31;
  const int ty = tid >> 5;           // 0..7: row within iteration
  const int lane = tid & 63;
  float4 uu = *(const float4*)(u + c4 * 4);
  float4 vv = *(const float4*)(v + c4 * 4);
  const int base = blockIdx.x * 64;
  #pragma unroll
  for (int it = 0; it < 8; ++it) {
    int r = base + it * 8 + ty;
    float4 xv = *(const float4*)(x + (size_t)r * FDIM + c4 * 4);
    float ps = xv.x * uu.x + xv.y * uu.y + xv.z * uu.z + xv.w * uu.w;
    float pd = xv.x * vv.x + xv.y * vv.y + xv.z * vv.z + xv.w * vv.w;
    #pragma unroll
    for (int o = 16; o > 0; o >>= 1) { ps += __shfl_xor(ps, o); pd += __shfl_xor(pd, o); }
    if ((lane & 31) == 0) {
      as_[r] = ps;
      ad_[r] = pd;
      denom[r] = __expf(lrelu(ps + pd));   // self-loop seeds denominator
    }
  }
}

// ---------------- fused partition: LDS histogram -> global base reservation ->
// LDS-cursor scatter (contiguous ~25-record runs per bucket per block, same
// write pattern as the old 3-pass pC). Buckets own fixed CAP-sized regions;
// cnt_* (pre-zeroed) hold final counts for the consumers.
__global__ __launch_bounds__(256) void k_scat(
    const int* __restrict__ ei, int* __restrict__ cnt_d, int* __restrict__ cnt_s,
    unsigned int* __restrict__ part_d, unsigned int* __restrict__ part_s) {
  __shared__ int hd[NB], hs[NB];   // histogram, then cursors
  __shared__ int bd[NB], bs[NB];   // reserved base offsets within bucket regions
  const int tid = threadIdx.x;
  const int chunk = blockIdx.x, t = blockIdx.y;
  if (tid < NB) { hd[tid] = 0; hs[tid] = 0; }
  __syncthreads();
  const int* eis = ei + (size_t)t * 2 * NEDGES;
  for (int i = tid; i < EC; i += 256) {   // pass 1: histogram (both axes)
    int e = chunk * EC + i;
    atomicAdd(&hd[eis[NEDGES + e] >> 7], 1);
    atomicAdd(&hs[eis[e] >> 7], 1);
  }
  __syncthreads();
  if (tid < NB) {                          // reserve global bases; reset cursors
    bd[tid] = atomicAdd(&cnt_d[t * NB + tid], hd[tid]);
    bs[tid] = atomicAdd(&cnt_s[t * NB + tid], hs[tid]);
    hd[tid] = 0; hs[tid] = 0;
  }
  __syncthreads();
  unsigned int* pdt = part_d + (size_t)t * NB * CAP;
  unsigned int* pst = part_s + (size_t)t * NB * CAP;
  for (int i = tid; i < EC; i += 256) {   // pass 2: scatter (ei re-read is L2-hot)
    int e = chunk * EC + i;
    int s = eis[e], d = eis[NEDGES + e];
    unsigned int rec = ((unsigned int)s << 15) | (unsigned int)d;
    int Bd = d >> 7, Bs = s >> 7;
    int od = bd[Bd] + atomicAdd(&hd[Bd], 1);
    pdt[Bd * CAP + od] = rec;
    int os = bs[Bs] + atomicAdd(&hs[Bs], 1);
    pst[Bs * CAP + os] = rec;
  }
}

// ---------------- denominator from dst-partition; aux=(ad,1/denom) fused
__global__ __launch_bounds__(256) void k_denomB(
    const unsigned int* __restrict__ part_d, const int* __restrict__ cnt_d,
    const float* __restrict__ as_, const float* __restrict__ ad_,
    const float* __restrict__ dseed, float2* __restrict__ aux) {
  __shared__ float hist[128];
  __shared__ float adl[128];
  const int tid = threadIdx.x;
  const int B = blockIdx.x, t = blockIdx.y;
  if (tid < 128) {
    hist[tid] = 0.f;
    int n = B * 128 + tid;
    adl[tid] = (n < NNODES) ? ad_[t * NNODES + n] : 0.f;
  }
  __syncthreads();
  const int cnt = cnt_d[t * NB + B];
  const unsigned int* pdt = part_d + ((size_t)t * NB + B) * CAP;
  const float* asb = as_ + (size_t)t * NNODES;
  for (int i = tid; i < cnt; i += 256) {
    unsigned int rec = pdt[i];
    int d = rec & 32767, s = rec >> 15;
    float w = __expf(lrelu(asb[s] + adl[d & 127]));
    atomicAdd(&hist[d & 127], w);
  }
  __syncthreads();
  if (tid < 128) {
    int n = B * 128 + tid;
    if (n < NNODES) {
      float den = dseed[t * NNODES + n] + hist[tid];
      aux[t * NNODES + n] = make_float2(adl[tid], 1.0f / den);
    }
  }
}

// ---------------- batch segment starts (batch is sorted)
__global__ void k_starts(const int* __restrict__ batch, int* __restrict__ starts) {
  int n = blockIdx.x * 256 + threadIdx.x;
  if (n >= NNODES) return;
  int b = batch[n];
  if (n == 0) { for (int bb = 0; bb <= b; ++bb) starts[bb] = 0; }
  else { int pb = batch[n - 1]; for (int bb = pb + 1; bb <= b; ++bb) starts[bb] = n; }
  if (n == NNODES - 1) { for (int bb = b + 1; bb <= BGR; ++bb) starts[bb] = NNODES; }
}

// ---------------- FUSED c-build + P-partial per (t, src-bucket B).
// LDS: cl stride 133 (odd -> cv broadcast addrs on 16 banks, 2-way free),
// x-tile 8 rows -> 38.8 KB total -> 4 blocks/CU.
__global__ __launch_bounds__(256) void k_cpgemm(
    const unsigned int* __restrict__ part_s, const int* __restrict__ cnt_s,
    const float* __restrict__ as_, const float2* __restrict__ aux,
    const int* __restrict__ batch, const float* __restrict__ x,
    float* __restrict__ ppart) {
  __shared__ float cl[BGR * CLSC];  // 34.0 KB
  __shared__ float asl[128];
  __shared__ float xs[8][XLS];      // 4.2 KB
  const int tid = threadIdx.x;
  const int B = blockIdx.x, t = blockIdx.y;
  #pragma unroll
  for (int i = tid; i < BGR * CLSC; i += 256) cl[i] = 0.f;
  if (tid < 128) {
    int n = B * 128 + tid;
    asl[tid] = (n < NNODES) ? as_[t * NNODES + n] : 0.f;
  }
  __syncthreads();
  if (tid < 128) {   // self-loop coefficient
    int n = B * 128 + tid;
    if (n < NNODES) {
      float2 a2 = aux[t * NNODES + n];
      float wself = __expf(lrelu(asl[tid] + a2.x)) * a2.y;
      cl[batch[n] * CLSC + tid] = wself;
    }
  }
  __syncthreads();
  {
    const int cnt = cnt_s[t * NB + B];
    const unsigned int* pst = part_s + ((size_t)t * NB + B) * CAP;
    const float2* auxt = aux + (size_t)t * NNODES;
    for (int i = tid; i < cnt; i += 256) {
      unsigned int rec = pst[i];
      int d = rec & 32767, s = rec >> 15;
      float2 a2 = auxt[d];
      float w = __expf(lrelu(asl[s & 127] + a2.x)) * a2.y;
      atomicAdd(&cl[batch[d] * CLSC + (s & 127)], w);
    }
  }
  // phase 2: [64 x 128] = cl[64 x 128k] @ x[128k x 128d], 8-row x tiles
  const int bq = tid >> 4;   // 4 b-rows each
  const int dq = tid & 15;   // cols {dq*4..+3} U {64+dq*4..+3}
  const float* xbase = x + (size_t)t * NNODES * FDIM;
  float acc[4][8] = {};
  for (int kt = 0; kt < 128; kt += 8) {
    __syncthreads();
    {
      int r = tid >> 5, c4 = (tid & 31) * 4;   // 256 threads = exactly 8x32 float4
      int row = B * 128 + kt + r;
      row = (row < NNODES) ? row : (NNODES - 1);   // clamp: cl coeff is 0 there
      *(float4*)&xs[r][c4] = *(const float4*)(xbase + (size_t)row * FDIM + c4);
    }
    __syncthreads();
    #pragma unroll
    for (int kk = 0; kk < 8; ++kk) {
      float cv[4];
      #pragma unroll
      for (int i = 0; i < 4; ++i) cv[i] = cl[(bq * 4 + i) * CLSC + kt + kk];
      float xd[8];
      *(float4*)&xd[0] = *(const float4*)&xs[kk][dq * 4];
      *(float4*)&xd[4] = *(const float4*)&xs[kk][64 + dq * 4];
      #pragma unroll
      for (int i = 0; i < 4; ++i)
        #pragma unroll
        for (int d = 0; d < 8; ++d)
          acc[i][d] += cv[i] * xd[d];
    }
  }
  float* pp = ppart + ((size_t)t * NB + B) * BGR * HDIM;
  #pragma unroll
  for (int i = 0; i < 4; ++i) {
    *(float4*)(pp + (bq * 4 + i) * HDIM + dq * 4)      = make_float4(acc[i][0], acc[i][1], acc[i][2], acc[i][3]);
    *(float4*)(pp + (bq * 4 + i) * HDIM + 64 + dq * 4) = make_float4(acc[i][4], acc[i][5], acc[i][6], acc[i][7]);
  }
}

// ---------------- pooled = (sum_B P) @ W * invc + gat_bias  (block per (t,b))
// W read directly (coalesced across d; 64 KB, L2-hot) -> no wT needed.
__global__ __launch_bounds__(128) void k_pw(
    const float* __restrict__ ppart, const int* __restrict__ starts,
    const float* __restrict__ W, const float* __restrict__ gat_bias,
    float* __restrict__ pooled) {
  __shared__ float srow[128];
  const int tb = blockIdx.x;       // 0..511
  const int t = tb >> 6, b = tb & 63;
  const int d = threadIdx.x;
  float s = 0.f;
  const float* pp = ppart + ((size_t)t * NB * BGR + b) * HDIM + d;
  #pragma unroll 4
  for (int B = 0; B < NB; ++B) s += pp[(size_t)B * BGR * HDIM];
  srow[d] = s;
  __syncthreads();
  const float invc = 1.0f / (float)max(starts[b + 1] - starts[b], 1);
  float o = 0.f;
  #pragma unroll 8
  for (int k = 0; k < 128; ++k) o += srow[k] * W[k * 128 + d];
  pooled[(size_t)(t * BGR + b) * HDIM + d] = o * invc + gat_bias[d];
}

// ---------------- LSTM over T + fused FC (one block per batch row b)
__global__ __launch_bounds__(512) void k_lstm_fc(
    const float* __restrict__ pooled,
    const float* __restrict__ W_ih, const float* __restrict__ W_hh,
    const float* __restrict__ b_ih, const float* __restrict__ b_hh,
    const float* __restrict__ z, const float* __restrict__ fc_W,
    const float* __restrict__ fc_b, float* __restrict__ out) {
  const int b = blockIdx.x;
  const int g = threadIdx.x;
  __shared__ unsigned int wpk[512 * 65];
  __shared__ float hv[128], cv[128], part[512];
  __shared__ float pool8[TT][128];
  __shared__ float fcp[16][17];

  #pragma unroll 2
  for (int it = 0; it < 64; ++it) {
    int i = g + it * 512;
    int gr = i >> 6, j = i & 63;
    float2 wv = *(const float2*)(W_hh + (size_t)gr * HDIM + j * 2);
    wpk[gr * 65 + j] = (unsigned int)f2bf(wv.x) | ((unsigned int)f2bf(wv.y) << 16);
  }
  #pragma unroll
  for (int i = 0; i < 2; ++i) {
    int idx = g + i * 512;
    int t = idx >> 7, k = idx & 127;
    pool8[t][k] = pooled[((size_t)t * BGR + b) * HDIM + k];
  }
  if (g < 128) { hv[g] = 0.f; cv[g] = 0.f; }
  __syncthreads();

  float gx[8] = {};
  {
    const float4* wi = (const float4*)(W_ih + (size_t)g * HDIM);
    #pragma unroll 2
    for (int k4 = 0; k4 < 32; ++k4) {
      float4 wv = wi[k4];
      #pragma unroll
      for (int t = 0; t < TT; ++t) {
        float4 p = *(const float4*)(&pool8[t][k4 * 4]);
        gx[t] += wv.x * p.x + wv.y * p.y + wv.z * p.z + wv.w * p.w;
      }
    }
  }
  const float bsum = b_ih[g] + b_hh[g];
  const unsigned int* wr = &wpk[g * 65];
  const float4* hv4 = (const float4*)hv;
  #pragma unroll
  for (int t = 0; t < TT; ++t) {
    float s = gx[t] + bsum;
    #pragma unroll 8
    for (int j2 = 0; j2 < 32; ++j2) {
      unsigned int w0 = wr[2 * j2], w1 = wr[2 * j2 + 1];
      float4 hh = hv4[j2];
      s += bf_lo(w0) * hh.x + bf_hi(w0) * hh.y + bf_lo(w1) * hh.z + bf_hi(w1) * hh.w;
    }
    part[g] = s;
    __syncthreads();
    if (g < 128) {
      float ig = sigmoidf(part[g]);
      float fg = sigmoidf(part[128 + g]);
      float gc = tanh_fast(part[256 + g]);
      float og = sigmoidf(part[384 + g]);
      float c = fg * cv[g] + ig * gc;
      cv[g] = c;
      hv[g] = og * tanh_fast(c);
    }
    __syncthreads();
  }
  if (g < 256) {
    const int c = g >> 4, kp = g & 15;
    float s = 0.f;
    for (int k = kp * 16; k < kp * 16 + 16; ++k) {
      float v = (k < 128) ? hv[k] : z[(size_t)b * HDIM + (k - 128)];
      s += v * fc_W[(size_t)c * 256 + k];
    }
    fcp[c][kp] = s;
  }
  __syncthreads();
  if (g < 16) {
    float r = fc_b[g];
    #pragma unroll
    for (int k = 0; k < 16; ++k) r += fcp[g][k];
    out[(size_t)b * NCLS + g] = r;
  }
}

extern "C" void kernel_launch(void* const* d_in, const int* in_sizes, int n_in,
                              void* d_out, int out_size, void* d_ws, size_t ws_size,
                              hipStream_t stream) {
  const float* x       = (const float*)d_in[0];
  const int*   ei      = (const int*)d_in[1];
  const int*   batch   = (const int*)d_in[2];
  const float* z       = (const float*)d_in[3];
  const float* gat_W   = (const float*)d_in[4];
  const float* att_src = (const float*)d_in[5];
  const float* att_dst = (const float*)d_in[6];
  const float* gat_bias= (const float*)d_in[7];
  const float* W_ih    = (const float*)d_in[8];
  const float* W_hh    = (const float*)d_in[9];
  const float* b_ih    = (const float*)d_in[10];
  const float* b_hh    = (const float*)d_in[11];
  const float* fc_W    = (const float*)d_in[12];
  const float* fc_b    = (const float*)d_in[13];
  float* out = (float*)d_out;

  char* ws = (char*)d_ws;
  size_t off = 0;
  auto alloc = [&](size_t bytes) {
    void* p = (void*)(ws + off);
    off += (bytes + 255) & ~(size_t)255;
    return p;
  };
  float*  as_    = (float*)alloc((size_t)TT * NNODES * 4);
  float*  ad_    = (float*)alloc((size_t)TT * NNODES * 4);
  float*  denom  = (float*)alloc((size_t)TT * NNODES * 4);
  float2* aux    = (float2*)alloc((size_t)TT * NNODES * 8);
  int*    cnt2   = (int*)alloc((size_t)2 * TT * NB * 4);            // cnt_d | cnt_s
  int*    cnt_d  = cnt2;
  int*    cnt_s  = cnt2 + TT * NB;
  unsigned int* part_d = (unsigned int*)alloc(((size_t)TT * NB + 1) * CAP * 4);   // 14.2 MB (+slack)
  unsigned int* part_s = (unsigned int*)alloc(((size_t)TT * NB + 1) * CAP * 4);   // 14.2 MB
  float* ppart = (float*)alloc((size_t)TT * NB * BGR * HDIM * 4);                 // 41.2 MB
  float* uvec  = (float*)alloc(128 * 4);
  float* vvec  = (float*)alloc(128 * 4);
  float* pooled = (float*)alloc((size_t)TT * BGR * HDIM * 4);
  int* starts = (int*)alloc((BGR + 1) * 4);
  (void)ws_size; (void)in_sizes; (void)n_in; (void)out_size;

  hipMemsetAsync(cnt2, 0, (size_t)2 * TT * NB * 4, stream);

  k_prep<<<1, 256, 0, stream>>>(gat_W, att_src, att_dst, uvec, vvec);
  k_gemv<<<(TT * NNODES) / 64, 256, 0, stream>>>(x, uvec, vvec, as_, ad_, denom);
  k_scat<<<dim3(CB, TT), 256, 0, stream>>>(ei, cnt_d, cnt_s, part_d, part_s);
  k_denomB<<<dim3(NB, TT), 256, 0, stream>>>(part_d, cnt_d, as_, ad_, denom, aux);
  k_starts<<<(NNODES + 255) / 256, 256, 0, stream>>>(batch, starts);
  k_cpgemm<<<dim3(NB, TT), 256, 0, stream>>>(part_s, cnt_s, as_, aux, batch, x, ppart);
  k_pw<<<TT * BGR, 128, 0, stream>>>(ppart, starts, gat_W, gat_bias, pooled);
  k_lstm_fc<<<BGR, 512, 0, stream>>>(pooled, W_ih, W_hh, b_ih, b_hh, z, fc_W, fc_b, out);
}

// Round 18
// 200.530 us; speedup vs baseline: 1.6589x; 1.0641x over previous
//
#include <hip/hip_runtime.h>
#include <math.h>

#define TT 8
#define NNODES 20000
#define NEDGES 320000
#define FDIM 128
#define HDIM 128
#define BGR 64
#define NCLS 16
#define NB 157    // radix buckets of 128 nodes (157*128 = 20096 >= 20000)
#define CB 80     // edge chunks per timestep
#define EC 4000   // edges per chunk (80*4000 = 320000)
#define CAP 2816  // bucket region capacity (mean 2048, sigma~45 -> +17 sigma)
#define CLSC 133  // c-tile LDS row stride

__device__ __forceinline__ float lrelu(float x) { return fmaxf(x, 0.2f * x); }
__device__ __forceinline__ float sigmoidf(float x) { return 1.0f / (1.0f + __expf(-x)); }
__device__ __forceinline__ float tanh_fast(float x) {
  return 1.0f - 2.0f / (__expf(2.0f * x) + 1.0f);
}
__device__ __forceinline__ unsigned short f2bf(float f) {   // RNE
  unsigned int u = __float_as_uint(f);
  unsigned int r = (u + 0x7fff + ((u >> 16) & 1)) >> 16;
  return (unsigned short)r;
}
__device__ __forceinline__ float bf_lo(unsigned int u) { return __uint_as_float(u << 16); }
__device__ __forceinline__ float bf_hi(unsigned int u) { return __uint_as_float(u & 0xffff0000u); }

// ---------------- prep: u = W@att_src, v = W@att_dst (one block, one-time)
__global__ __launch_bounds__(256) void k_prep(
    const float* __restrict__ W, const float* __restrict__ att_s, const float* __restrict__ att_d,
    float* __restrict__ u, float* __restrict__ v) {
  const int tid = threadIdx.x;
  if (tid < 128) {
    float su = 0.f, sv = 0.f;
    const float4* wr = (const float4*)(W + (size_t)tid * 128);
    #pragma unroll 8
    for (int q = 0; q < 32; ++q) {
      float4 w4 = wr[q];
      float4 a4 = *(const float4*)(att_s + q * 4);
      float4 d4 = *(const float4*)(att_d + q * 4);
      su += w4.x * a4.x + w4.y * a4.y + w4.z * a4.z + w4.w * a4.w;
      sv += w4.x * d4.x + w4.y * d4.y + w4.z * d4.z + w4.w * d4.w;
    }
    u[tid] = su; v[tid] = sv;
  }
}

// ---------------- GEMV: as = x@u, ad = x@v over all T*N rows; denom seed fused.
__global__ __launch_bounds__(256) void k_gemv(
    const float* __restrict__ x, const float* __restrict__ u, const float* __restrict__ v,
    float* __restrict__ as_, float* __restrict__ ad_, float* __restrict__ denom) {
  const int tid = threadIdx.x;
  const int c4 = tid & 31;
  const int ty = tid >> 5;           // 0..7: row within iteration
  const int lane = tid & 63;
  float4 uu = *(const float4*)(u + c4 * 4);
  float4 vv = *(const float4*)(v + c4 * 4);
  const int base = blockIdx.x * 64;
  #pragma unroll
  for (int it = 0; it < 8; ++it) {
    int r = base + it * 8 + ty;
    float4 xv = *(const float4*)(x + (size_t)r * FDIM + c4 * 4);
    float ps = xv.x * uu.x + xv.y * uu.y + xv.z * uu.z + xv.w * uu.w;
    float pd = xv.x * vv.x + xv.y * vv.y + xv.z * vv.z + xv.w * vv.w;
    #pragma unroll
    for (int o = 16; o > 0; o >>= 1) { ps += __shfl_xor(ps, o); pd += __shfl_xor(pd, o); }
    if ((lane & 31) == 0) {
      as_[r] = ps;
      ad_[r] = pd;
      denom[r] = __expf(lrelu(ps + pd));   // self-loop seeds denominator
    }
  }
}

// ---------------- fused partition, SINGLE ei read: records buffered in LDS during
// histogram pass; global base reservation; scatter from LDS. 18.6 KB -> 8 blocks/CU.
__global__ __launch_bounds__(256) void k_scat(
    const int* __restrict__ ei, int* __restrict__ cnt_d, int* __restrict__ cnt_s,
    unsigned int* __restrict__ part_d, unsigned int* __restrict__ part_s) {
  __shared__ unsigned int buf[EC];  // 16 KB record buffer
  __shared__ int hd[NB], hs[NB];    // histogram, then cursors
  __shared__ int bd[NB], bs[NB];    // reserved base offsets
  const int tid = threadIdx.x;
  const int chunk = blockIdx.x, t = blockIdx.y;
  if (tid < NB) { hd[tid] = 0; hs[tid] = 0; }
  __syncthreads();
  const int* eis = ei + (size_t)t * 2 * NEDGES;
  for (int i = tid; i < EC; i += 256) {   // pass 1: read once, buffer + histogram
    int e = chunk * EC + i;
    int s = eis[e], d = eis[NEDGES + e];
    buf[i] = ((unsigned int)s << 15) | (unsigned int)d;
    atomicAdd(&hd[d >> 7], 1);
    atomicAdd(&hs[s >> 7], 1);
  }
  __syncthreads();
  if (tid < NB) {                          // reserve global bases; reset cursors
    bd[tid] = atomicAdd(&cnt_d[t * NB + tid], hd[tid]);
    bs[tid] = atomicAdd(&cnt_s[t * NB + tid], hs[tid]);
    hd[tid] = 0; hs[tid] = 0;
  }
  __syncthreads();
  unsigned int* pdt = part_d + (size_t)t * NB * CAP;
  unsigned int* pst = part_s + (size_t)t * NB * CAP;
  for (int i = tid; i < EC; i += 256) {   // pass 2: scatter from LDS
    unsigned int rec = buf[i];
    int d = rec & 32767, s = rec >> 15;
    int Bd = d >> 7, Bs = s >> 7;
    int od = bd[Bd] + atomicAdd(&hd[Bd], 1);
    pdt[Bd * CAP + od] = rec;
    int os = bs[Bs] + atomicAdd(&hs[Bs], 1);
    pst[Bs * CAP + os] = rec;
  }
}

// ---------------- denominator from dst-partition; aux4=(ad, 1/denom, batch-bits, 0)
// fused; k_starts folded in (t==0 blocks handle their 128-node slice).
__global__ __launch_bounds__(256) void k_denomB(
    const unsigned int* __restrict__ part_d, const int* __restrict__ cnt_d,
    const float* __restrict__ as_, const float* __restrict__ ad_,
    const float* __restrict__ dseed, const int* __restrict__ batch,
    float4* __restrict__ aux4, int* __restrict__ starts) {
  __shared__ float hist[128];
  __shared__ float adl[128];
  const int tid = threadIdx.x;
  const int B = blockIdx.x, t = blockIdx.y;
  if (tid < 128) {
    hist[tid] = 0.f;
    int n = B * 128 + tid;
    adl[tid] = (n < NNODES) ? ad_[t * NNODES + n] : 0.f;
  }
  __syncthreads();
  const int cnt = cnt_d[t * NB + B];
  const unsigned int* pdt = part_d + ((size_t)t * NB + B) * CAP;
  const float* asb = as_ + (size_t)t * NNODES;
  for (int i = tid; i < cnt; i += 256) {
    unsigned int rec = pdt[i];
    int d = rec & 32767, s = rec >> 15;
    float w = __expf(lrelu(asb[s] + adl[d & 127]));
    atomicAdd(&hist[d & 127], w);
  }
  __syncthreads();
  if (tid < 128) {
    int n = B * 128 + tid;
    if (n < NNODES) {
      float den = dseed[t * NNODES + n] + hist[tid];
      int bn = batch[n];
      aux4[t * NNODES + n] = make_float4(adl[tid], 1.0f / den, __int_as_float(bn), 0.f);
      if (t == 0) {   // folded k_starts (batch is sorted)
        if (n == 0) { for (int bb = 0; bb <= bn; ++bb) starts[bb] = 0; }
        else { int pb = batch[n - 1]; for (int bb = pb + 1; bb <= bn; ++bb) starts[bb] = n; }
        if (n == NNODES - 1) { for (int bb = bn + 1; bb <= BGR; ++bb) starts[bb] = NNODES; }
      }
    }
  }
}

// ---------------- FUSED c-build + P-partial per (t, src-bucket B).
// Phase 1: 4-deep pipelined edge pass (independent rec->aux4 gather chains),
//   LDS-atomic accumulate into cl. Phase 2: NO LDS x tile -- wave-uniform row
//   reads served by L1 (2x256B per row, 4x in-wave reuse); zero phase-2 barriers.
__global__ __launch_bounds__(256) void k_cpgemm(
    const unsigned int* __restrict__ part_s, const int* __restrict__ cnt_s,
    const float* __restrict__ as_, const float4* __restrict__ aux4,
    const float* __restrict__ x, float* __restrict__ ppart) {
  __shared__ float cl[BGR * CLSC];  // 34.0 KB
  __shared__ float asl[128];
  const int tid = threadIdx.x;
  const int B = blockIdx.x, t = blockIdx.y;
  #pragma unroll
  for (int i = tid; i < BGR * CLSC; i += 256) cl[i] = 0.f;
  if (tid < 128) {
    int n = B * 128 + tid;
    asl[tid] = (n < NNODES) ? as_[t * NNODES + n] : 0.f;
  }
  __syncthreads();
  const float4* auxt = aux4 + (size_t)t * NNODES;
  if (tid < 128) {   // self-loop coefficient
    int n = B * 128 + tid;
    if (n < NNODES) {
      float4 a2 = auxt[n];
      float wself = __expf(lrelu(asl[tid] + a2.x)) * a2.y;
      cl[__float_as_int(a2.z) * CLSC + tid] = wself;
    }
  }
  {
    const int cnt = cnt_s[t * NB + B];
    const unsigned int* pst = part_s + ((size_t)t * NB + B) * CAP;
    int i = tid;
    for (; i + 768 < cnt; i += 1024) {   // 4 independent chains in flight
      unsigned int r0 = pst[i], r1 = pst[i + 256], r2 = pst[i + 512], r3 = pst[i + 768];
      float4 a0 = auxt[r0 & 32767], a1 = auxt[r1 & 32767];
      float4 a2 = auxt[r2 & 32767], a3 = auxt[r3 & 32767];
      float w0 = __expf(lrelu(asl[r0 >> 15 & 127] + a0.x)) * a0.y;
      float w1 = __expf(lrelu(asl[r1 >> 15 & 127] + a1.x)) * a1.y;
      float w2 = __expf(lrelu(asl[r2 >> 15 & 127] + a2.x)) * a2.y;
      float w3 = __expf(lrelu(asl[r3 >> 15 & 127] + a3.x)) * a3.y;
      atomicAdd(&cl[__float_as_int(a0.z) * CLSC + (int)(r0 >> 15 & 127)], w0);
      atomicAdd(&cl[__float_as_int(a1.z) * CLSC + (int)(r1 >> 15 & 127)], w1);
      atomicAdd(&cl[__float_as_int(a2.z) * CLSC + (int)(r2 >> 15 & 127)], w2);
      atomicAdd(&cl[__float_as_int(a3.z) * CLSC + (int)(r3 >> 15 & 127)], w3);
    }
    for (; i < cnt; i += 256) {
      unsigned int rec = pst[i];
      int s7 = (int)(rec >> 15) & 127;
      float4 aa = auxt[rec & 32767];
      float w = __expf(lrelu(asl[s7] + aa.x)) * aa.y;
      atomicAdd(&cl[__float_as_int(aa.z) * CLSC + s7], w);
    }
  }
  __syncthreads();   // the ONLY barrier between phases
  // phase 2: [64 x 128] = cl @ x[bucket rows], x straight from L1/L2
  const int bq = tid >> 4;   // 4 b-rows each
  const int dq = tid & 15;   // cols {dq*4..+3} U {64+dq*4..+3}
  const float* xbase = x + (size_t)t * NNODES * FDIM;
  float acc[4][8] = {};
  #pragma unroll 4
  for (int kk = 0; kk < 128; ++kk) {
    int row = B * 128 + kk;
    row = (row < NNODES) ? row : (NNODES - 1);   // clamp: cl coeff is 0 there
    const float* xr = xbase + (size_t)row * FDIM;
    float xd[8];
    *(float4*)&xd[0] = *(const float4*)(xr + dq * 4);
    *(float4*)&xd[4] = *(const float4*)(xr + 64 + dq * 4);
    float cv[4];
    #pragma unroll
    for (int i = 0; i < 4; ++i) cv[i] = cl[(bq * 4 + i) * CLSC + kk];
    #pragma unroll
    for (int i = 0; i < 4; ++i)
      #pragma unroll
      for (int d = 0; d < 8; ++d)
        acc[i][d] += cv[i] * xd[d];
  }
  float* pp = ppart + ((size_t)t * NB + B) * BGR * HDIM;
  #pragma unroll
  for (int i = 0; i < 4; ++i) {
    *(float4*)(pp + (bq * 4 + i) * HDIM + dq * 4)      = make_float4(acc[i][0], acc[i][1], acc[i][2], acc[i][3]);
    *(float4*)(pp + (bq * 4 + i) * HDIM + 64 + dq * 4) = make_float4(acc[i][4], acc[i][5], acc[i][6], acc[i][7]);
  }
}

// ---------------- pooled = (sum_B P) @ W * invc + gat_bias  (block per (t,b))
__global__ __launch_bounds__(128) void k_pw(
    const float* __restrict__ ppart, const int* __restrict__ starts,
    const float* __restrict__ W, const float* __restrict__ gat_bias,
    float* __restrict__ pooled) {
  __shared__ float srow[128];
  const int tb = blockIdx.x;       // 0..511
  const int t = tb >> 6, b = tb & 63;
  const int d = threadIdx.x;
  float s = 0.f;
  const float* pp = ppart + ((size_t)t * NB * BGR + b) * HDIM + d;
  #pragma unroll 4
  for (int B = 0; B < NB; ++B) s += pp[(size_t)B * BGR * HDIM];
  srow[d] = s;
  __syncthreads();
  const float invc = 1.0f / (float)max(starts[b + 1] - starts[b], 1);
  float o = 0.f;
  #pragma unroll 8
  for (int k = 0; k < 128; ++k) o += srow[k] * W[k * 128 + d];
  pooled[(size_t)(t * BGR + b) * HDIM + d] = o * invc + gat_bias[d];
}

// ---------------- LSTM over T + fused FC (one block per batch row b)
__global__ __launch_bounds__(512) void k_lstm_fc(
    const float* __restrict__ pooled,
    const float* __restrict__ W_ih, const float* __restrict__ W_hh,
    const float* __restrict__ b_ih, const float* __restrict__ b_hh,
    const float* __restrict__ z, const float* __restrict__ fc_W,
    const float* __restrict__ fc_b, float* __restrict__ out) {
  const int b = blockIdx.x;
  const int g = threadIdx.x;
  __shared__ unsigned int wpk[512 * 65];
  __shared__ float hv[128], cv[128], part[512];
  __shared__ float pool8[TT][128];
  __shared__ float fcp[16][17];

  #pragma unroll 2
  for (int it = 0; it < 64; ++it) {
    int i = g + it * 512;
    int gr = i >> 6, j = i & 63;
    float2 wv = *(const float2*)(W_hh + (size_t)gr * HDIM + j * 2);
    wpk[gr * 65 + j] = (unsigned int)f2bf(wv.x) | ((unsigned int)f2bf(wv.y) << 16);
  }
  #pragma unroll
  for (int i = 0; i < 2; ++i) {
    int idx = g + i * 512;
    int t = idx >> 7, k = idx & 127;
    pool8[t][k] = pooled[((size_t)t * BGR + b) * HDIM + k];
  }
  if (g < 128) { hv[g] = 0.f; cv[g] = 0.f; }
  __syncthreads();

  float gx[8] = {};
  {
    const float4* wi = (const float4*)(W_ih + (size_t)g * HDIM);
    #pragma unroll 2
    for (int k4 = 0; k4 < 32; ++k4) {
      float4 wv = wi[k4];
      #pragma unroll
      for (int t = 0; t < TT; ++t) {
        float4 p = *(const float4*)(&pool8[t][k4 * 4]);
        gx[t] += wv.x * p.x + wv.y * p.y + wv.z * p.z + wv.w * p.w;
      }
    }
  }
  const float bsum = b_ih[g] + b_hh[g];
  const unsigned int* wr = &wpk[g * 65];
  const float4* hv4 = (const float4*)hv;
  #pragma unroll
  for (int t = 0; t < TT; ++t) {
    float s = gx[t] + bsum;
    #pragma unroll 8
    for (int j2 = 0; j2 < 32; ++j2) {
      unsigned int w0 = wr[2 * j2], w1 = wr[2 * j2 + 1];
      float4 hh = hv4[j2];
      s += bf_lo(w0) * hh.x + bf_hi(w0) * hh.y + bf_lo(w1) * hh.z + bf_hi(w1) * hh.w;
    }
    part[g] = s;
    __syncthreads();
    if (g < 128) {
      float ig = sigmoidf(part[g]);
      float fg = sigmoidf(part[128 + g]);
      float gc = tanh_fast(part[256 + g]);
      float og = sigmoidf(part[384 + g]);
      float c = fg * cv[g] + ig * gc;
      cv[g] = c;
      hv[g] = og * tanh_fast(c);
    }
    __syncthreads();
  }
  if (g < 256) {
    const int c = g >> 4, kp = g & 15;
    float s = 0.f;
    for (int k = kp * 16; k < kp * 16 + 16; ++k) {
      float v = (k < 128) ? hv[k] : z[(size_t)b * HDIM + (k - 128)];
      s += v * fc_W[(size_t)c * 256 + k];
    }
    fcp[c][kp] = s;
  }
  __syncthreads();
  if (g < 16) {
    float r = fc_b[g];
    #pragma unroll
    for (int k = 0; k < 16; ++k) r += fcp[g][k];
    out[(size_t)b * NCLS + g] = r;
  }
}

extern "C" void kernel_launch(void* const* d_in, const int* in_sizes, int n_in,
                              void* d_out, int out_size, void* d_ws, size_t ws_size,
                              hipStream_t stream) {
  const float* x       = (const float*)d_in[0];
  const int*   ei      = (const int*)d_in[1];
  const int*   batch   = (const int*)d_in[2];
  const float* z       = (const float*)d_in[3];
  const float* gat_W   = (const float*)d_in[4];
  const float* att_src = (const float*)d_in[5];
  const float* att_dst = (const float*)d_in[6];
  const float* gat_bias= (const float*)d_in[7];
  const float* W_ih    = (const float*)d_in[8];
  const float* W_hh    = (const float*)d_in[9];
  const float* b_ih    = (const float*)d_in[10];
  const float* b_hh    = (const float*)d_in[11];
  const float* fc_W    = (const float*)d_in[12];
  const float* fc_b    = (const float*)d_in[13];
  float* out = (float*)d_out;

  char* ws = (char*)d_ws;
  size_t off = 0;
  auto alloc = [&](size_t bytes) {
    void* p = (void*)(ws + off);
    off += (bytes + 255) & ~(size_t)255;
    return p;
  };
  float*  as_    = (float*)alloc((size_t)TT * NNODES * 4);
  float*  ad_    = (float*)alloc((size_t)TT * NNODES * 4);
  float*  denom  = (float*)alloc((size_t)TT * NNODES * 4);
  float4* aux4   = (float4*)alloc((size_t)TT * NNODES * 16);                      // 2.56 MB
  int*    cnt2   = (int*)alloc((size_t)2 * TT * NB * 4);            // cnt_d | cnt_s
  int*    cnt_d  = cnt2;
  int*    cnt_s  = cnt2 + TT * NB;
  unsigned int* part_d = (unsigned int*)alloc(((size_t)TT * NB + 1) * CAP * 4);   // 14.2 MB (+slack)
  unsigned int* part_s = (unsigned int*)alloc(((size_t)TT * NB + 1) * CAP * 4);   // 14.2 MB
  float* ppart = (float*)alloc((size_t)TT * NB * BGR * HDIM * 4);                 // 41.2 MB
  float* uvec  = (float*)alloc(128 * 4);
  float* vvec  = (float*)alloc(128 * 4);
  float* pooled = (float*)alloc((size_t)TT * BGR * HDIM * 4);
  int* starts = (int*)alloc((BGR + 1) * 4);
  (void)ws_size; (void)in_sizes; (void)n_in; (void)out_size;

  hipMemsetAsync(cnt2, 0, (size_t)2 * TT * NB * 4, stream);

  k_prep<<<1, 256, 0, stream>>>(gat_W, att_src, att_dst, uvec, vvec);
  k_gemv<<<(TT * NNODES) / 64, 256, 0, stream>>>(x, uvec, vvec, as_, ad_, denom);
  k_scat<<<dim3(CB, TT), 256, 0, stream>>>(ei, cnt_d, cnt_s, part_d, part_s);
  k_denomB<<<dim3(NB, TT), 256, 0, stream>>>(part_d, cnt_d, as_, ad_, denom, batch, aux4, starts);
  k_cpgemm<<<dim3(NB, TT), 256, 0, stream>>>(part_s, cnt_s, as_, aux4, x, ppart);
  k_pw<<<TT * BGR, 128, 0, stream>>>(ppart, starts, gat_W, gat_bias, pooled);
  k_lstm_fc<<<BGR, 512, 0, stream>>>(pooled, W_ih, W_hh, b_ih, b_hh, z, fc_W, fc_b, out);
}